// Round 7
// baseline (437.816 us; speedup 1.0000x reference)
//
#include <hip/hip_runtime.h>

typedef __bf16 bf16;
typedef __attribute__((ext_vector_type(8))) __bf16 bf16x8;
typedef __attribute__((ext_vector_type(4))) __bf16 bf16x4;
typedef __attribute__((ext_vector_type(4))) float f32x4;

static constexpr int Bc = 4, Tc = 2048, Dc = 1024, Hc = 16, HSc = 64, DFF = 4096;
static constexpr int Mrows = Bc * Tc;  // 8192

#define DEV __device__ __forceinline__

DEV void load_lds16(const void* g, void* l) {
  __builtin_amdgcn_global_load_lds(
      (const __attribute__((address_space(1))) void*)g,
      (__attribute__((address_space(3))) void*)l, 16, 0, 0);
}

// ---------------- weight repack: wq/wk/wv [H,D,HS] -> WqkvT [3072(n)][1024(k=d)] bf16
__global__ void repack_qkv_kernel(const float* __restrict__ wq,
                                  const float* __restrict__ wk,
                                  const float* __restrict__ wv,
                                  bf16* __restrict__ dst) {
  __shared__ float tile[64][65];
  const int dblk = blockIdx.x;
  const int z = blockIdx.y;
  const int w = z >> 4, h = z & 15;
  const float* src = (w == 0 ? wq : (w == 1 ? wk : wv)) + (size_t)h * Dc * HSc;
  const int tx = threadIdx.x, ty = threadIdx.y;
#pragma unroll
  for (int i = 0; i < 16; ++i)
    tile[ty + i * 4][tx] = src[(size_t)(dblk * 64 + ty + i * 4) * HSc + tx];
  __syncthreads();
#pragma unroll
  for (int i = 0; i < 16; ++i) {
    const int s = ty + i * 4;
    dst[((size_t)w * 1024 + h * 64 + s) * Dc + dblk * 64 + tx] = (bf16)tile[tx][s];
  }
}

// ---------------- generic [R][C] f32 -> [C][R] bf16 transpose
__global__ void transpose_to_bf16_kernel(const float* __restrict__ src,
                                         bf16* __restrict__ dst, int R, int C) {
  __shared__ float tile[64][65];
  const int r0 = blockIdx.x * 64, c0 = blockIdx.y * 64;
  const int tx = threadIdx.x, ty = threadIdx.y;
#pragma unroll
  for (int i = 0; i < 16; ++i)
    tile[ty + i * 4][tx] = src[(size_t)(r0 + ty + i * 4) * C + c0 + tx];
  __syncthreads();
#pragma unroll
  for (int i = 0; i < 16; ++i)
    dst[(size_t)(c0 + ty + i * 4) * R + r0 + tx] = (bf16)tile[tx][ty + i * 4];
}

// ---------------- LayerNorm row kernel: f32 in -> bf16 out
__global__ __launch_bounds__(256) void ln_kernel(const float* __restrict__ x,
                                                 const float* __restrict__ gam,
                                                 const float* __restrict__ bet,
                                                 bf16* __restrict__ out) {
  const int row = blockIdx.x;
  const int t = threadIdx.x;
  const float4 v = ((const float4*)(x + (size_t)row * Dc))[t];
  float s = v.x + v.y + v.z + v.w;
  float s2 = v.x * v.x + v.y * v.y + v.z * v.z + v.w * v.w;
#pragma unroll
  for (int m = 1; m < 64; m <<= 1) {
    s += __shfl_xor(s, m);
    s2 += __shfl_xor(s2, m);
  }
  __shared__ float red[8];
  const int wid = t >> 6;
  if ((t & 63) == 0) { red[wid * 2] = s; red[wid * 2 + 1] = s2; }
  __syncthreads();
  s = red[0] + red[2] + red[4] + red[6];
  s2 = red[1] + red[3] + red[5] + red[7];
  const float mean = s * (1.f / Dc);
  const float var = s2 * (1.f / Dc) - mean * mean;
  const float rstd = rsqrtf(var + 1e-5f);
  const float4 gv = ((const float4*)gam)[t];
  const float4 bv = ((const float4*)bet)[t];
  bf16x4 o;
  o[0] = (bf16)((v.x - mean) * rstd * gv.x + bv.x);
  o[1] = (bf16)((v.y - mean) * rstd * gv.y + bv.y);
  o[2] = (bf16)((v.z - mean) * rstd * gv.z + bv.z);
  o[3] = (bf16)((v.w - mean) * rstd * gv.w + bv.w);
  *(bf16x4*)(out + (size_t)row * Dc + t * 4) = o;
}

// ---------------- GEMM v4: BM=256, BK=32, 8 waves, per-wave 64-col tiles
// (BN=256: 2Mx4N waves -> 128x64/wave; BN=128: 4Mx2N -> 64x64/wave).
// 4-buffer rotation, prefetch depth 3, counted vmcnt(2L) gate, ONE barrier
// per K-tile, (row>>1)&3 16B-unit XOR swizzle both-sides, counted lgkmcnt,
// setprio. Identity block mapping (L3 serves inter-block reuse).
template <int MODE, int KTOT, int BN>
__global__ __launch_bounds__(512, 1) void gemm4p_kernel(
    const bf16* __restrict__ A, const bf16* __restrict__ BT,
    const float* __restrict__ bias, const float* __restrict__ resid,
    float* __restrict__ outf, bf16* __restrict__ outb,
    bf16* __restrict__ qo, bf16* __restrict__ ko, bf16* __restrict__ vto) {
  constexpr int NT = KTOT / 32;
  constexpr int L = (BN == 256) ? 4 : 3;   // gload_lds calls per K-tile
  constexpr int WN = (BN == 256) ? 4 : 2;  // waves along N
  constexpr int MW = (BN == 256) ? 128 : 64;  // per-wave rows
  constexpr int NAF = MW / 16;             // A-frags per wave (8 or 4)
  constexpr int NSTR = (MODE == 2) ? 4096 : 1024;
  constexpr int ABUF = 256 * 32 * 2;       // bytes per A buffer (16KB)
  constexpr int BBUF = BN * 32 * 2;        // bytes per B buffer

  __shared__ __attribute__((aligned(16))) bf16 As[4][256 * 32];
  __shared__ __attribute__((aligned(16))) bf16 Bs[4][BN * 32];

  const int tid = threadIdx.x;
  const int wid = tid >> 6, lane = tid & 63;
  const int g = (lane >> 4) & 3, c = lane & 15;
  const int wm = wid / WN, wn = wid % WN;
  const int bm = blockIdx.x, bn = blockIdx.y;

  f32x4 acc[NAF][4];
#pragma unroll
  for (int i = 0; i < NAF; ++i)
#pragma unroll
    for (int j = 0; j < 4; ++j)
#pragma unroll
      for (int r = 0; r < 4; ++r) acc[i][j][r] = 0.f;

  // staging: thread tid covers LDS row tid>>2, 16B-unit tid&3 (per 8KB call);
  // source fetches global unit (tid&3)^((tid>>3)&3)  [inverse of read swizzle]
  const int sof = ((tid & 3) ^ ((tid >> 3) & 3)) << 4;
  const char* Agl = (const char*)A;
  const char* Bgl = (const char*)BT;

  auto stage = [&](int kt) {
    const int buf = kt & 3;
    const size_t kb = (size_t)kt * 64;  // col byte offset
#pragma unroll
    for (int a = 0; a < 2; ++a)
      load_lds16(Agl + ((size_t)(bm * 256 + a * 128 + (tid >> 2)) * KTOT) * 2 + kb + sof,
                 (char*)&As[buf][0] + a * 8192 + tid * 16);
    if (BN == 256) {
#pragma unroll
      for (int a = 0; a < 2; ++a)
        load_lds16(Bgl + ((size_t)(bn * 256 + a * 128 + (tid >> 2)) * KTOT) * 2 + kb + sof,
                   (char*)&Bs[buf][0] + a * 8192 + tid * 16);
    } else {
      load_lds16(Bgl + ((size_t)(bn * 128 + (tid >> 2)) * KTOT) * 2 + kb + sof,
                 (char*)&Bs[buf][0] + tid * 16);
    }
  };

  stage(0);
  stage(1);
  stage(2);

  for (int t = 0; t < NT; ++t) {
    // gate: this wave's tile-t loads done (keep t+1,t+2 in flight), then all waves
    if (t + 2 < NT) {
      asm volatile("s_waitcnt vmcnt(%0)" ::"i"(2 * L) : "memory");
    } else if (t + 1 < NT) {
      asm volatile("s_waitcnt vmcnt(%0)" ::"i"(L) : "memory");
    } else {
      asm volatile("s_waitcnt vmcnt(0)" ::: "memory");
    }
    __builtin_amdgcn_s_barrier();
    if (t + 3 < NT) stage(t + 3);

    const char* Ab = (const char*)As + (t & 3) * ABUF;
    const char* Bb = (const char*)Bs + (t & 3) * BBUF;
    bf16x8 bfr[4], af[NAF];
#pragma unroll
    for (int j = 0; j < 4; ++j) {
      const int row = wn * 64 + j * 16 + c;
      bfr[j] = *(const bf16x8*)(Bb + row * 64 + ((g * 16) ^ (((row >> 1) & 3) << 4)));
    }
#pragma unroll
    for (int i = 0; i < NAF; ++i) {
      const int row = wm * MW + i * 16 + c;
      af[i] = *(const bf16x8*)(Ab + row * 64 + ((g * 16) ^ (((row >> 1) & 3) << 4)));
    }
    if (NAF == 8) {
      asm volatile("s_waitcnt lgkmcnt(4)" ::: "memory");  // bfr0-3 + af0-3 done
    } else {
      asm volatile("s_waitcnt lgkmcnt(0)" ::: "memory");
    }
    __builtin_amdgcn_sched_barrier(0);
    __builtin_amdgcn_s_setprio(1);
#pragma unroll
    for (int i = 0; i < 4; ++i)
#pragma unroll
      for (int j = 0; j < 4; ++j)
        acc[i][j] = __builtin_amdgcn_mfma_f32_16x16x32_bf16(af[i], bfr[j], acc[i][j], 0, 0, 0);
    __builtin_amdgcn_s_setprio(0);
    if (NAF == 8) {
      asm volatile("s_waitcnt lgkmcnt(0)" ::: "memory");
      __builtin_amdgcn_sched_barrier(0);
      __builtin_amdgcn_s_setprio(1);
#pragma unroll
      for (int i = 4; i < NAF; ++i)
#pragma unroll
        for (int j = 0; j < 4; ++j)
          acc[i][j] = __builtin_amdgcn_mfma_f32_16x16x32_bf16(af[i], bfr[j], acc[i][j], 0, 0, 0);
      __builtin_amdgcn_s_setprio(0);
    }
  }

  // epilogue: rows m0 = bm*256+wm*MW+fr*16+g*4 (+r), col n = bn*BN+wn*64+nf*16+c
#pragma unroll
  for (int nf = 0; nf < 4; ++nf) {
    const int n = bn * BN + wn * 64 + nf * 16 + c;
    float bi = 0.f;
    if (MODE != 0) bi = bias[n];
#pragma unroll
    for (int fr = 0; fr < NAF; ++fr) {
      const int m0 = bm * 256 + wm * MW + fr * 16 + g * 4;
      if (MODE == 0) {
        const int w = n >> 10, n1 = n & 1023, h = n1 >> 6, sidx = n1 & 63;
        const int b2 = m0 >> 11, t0 = m0 & 2047;
        if (w == 0) {
#pragma unroll
          for (int r = 0; r < 4; ++r)
            qo[(size_t)(b2 * Hc + h) * (Tc * HSc) + (size_t)(t0 + r) * HSc + sidx] =
                (bf16)(acc[fr][nf][r] * 0.125f);
        } else if (w == 1) {
#pragma unroll
          for (int r = 0; r < 4; ++r)
            ko[(size_t)(b2 * Hc + h) * (Tc * HSc) + (size_t)(t0 + r) * HSc + sidx] =
                (bf16)acc[fr][nf][r];
        } else {
          bf16x4 pk;
#pragma unroll
          for (int r = 0; r < 4; ++r) pk[r] = (bf16)acc[fr][nf][r];
          *(bf16x4*)&vto[((size_t)(b2 * Hc + h) * HSc + sidx) * Tc + t0] = pk;
        }
      } else if (MODE == 1 || MODE == 3) {
#pragma unroll
        for (int r = 0; r < 4; ++r) {
          const size_t idx = (size_t)(m0 + r) * NSTR + n;
          outf[idx] = acc[fr][nf][r] + bi + resid[idx];
        }
      } else {
#pragma unroll
        for (int r = 0; r < 4; ++r)
          outb[(size_t)(m0 + r) * NSTR + n] = (bf16)fmaxf(acc[fr][nf][r] + bi, 0.f);
      }
    }
  }
}

// ---------------- causal flash attention (unchanged from R3)
__global__ __launch_bounds__(256, 2) void attn_kernel(const bf16* __restrict__ q,
                                                      const bf16* __restrict__ k,
                                                      const bf16* __restrict__ vt,
                                                      bf16* __restrict__ ctx) {
  __shared__ __attribute__((aligned(16))) bf16 Kl[2][4096];
  __shared__ __attribute__((aligned(16))) bf16 Vl[2][4096];
  __shared__ __attribute__((aligned(16))) bf16 P[4][32][72];
  const int d0 = blockIdx.x;
  const int L = (d0 & 7) * 64 + (d0 >> 3);
  const int bh = L >> 3, p = L & 7;
  const int tid = threadIdx.x;
  const int wid = tid >> 6, lane = tid & 63;
  const int g = lane >> 4, c = lane & 15;
  const bf16* qh = q + (size_t)bh * Tc * HSc;
  const char* kh = (const char*)(k + (size_t)bh * Tc * HSc);
  const char* vh = (const char*)(vt + (size_t)bh * HSc * Tc);
  const int b = bh >> 4, h = bh & 15;

  const int sw = ((lane >> 3) & 7) << 4;
  const int soK = (lane * 16) ^ sw;
  const int vrow = lane >> 3;
  const int vcol = ((lane & 7) * 16) ^ sw;
  const int rsw = (c & 7) << 4;

  for (int g2 = 0; g2 < 2; ++g2) {
    const int grp = g2 ? p : 15 - p;
    const int ktB = 2 * grp + 1;
    const int ktW = 2 * grp + (wid >> 1);
    const int row0 = grp * 128 + wid * 32;
    const bf16* qb = qh + (size_t)row0 * HSc;

    bf16x8 qf[2][2];
#pragma unroll
    for (int mi = 0; mi < 2; ++mi)
#pragma unroll
      for (int kk = 0; kk < 2; ++kk)
        qf[mi][kk] = *(const bf16x8*)&qb[(size_t)(mi * 16 + c) * HSc + kk * 32 + g * 8];

    f32x4 o[2][4];
    float m_[2][4], ls[2][4];
#pragma unroll
    for (int mi = 0; mi < 2; ++mi)
#pragma unroll
      for (int r = 0; r < 4; ++r) {
        m_[mi][r] = -1e30f;
        ls[mi][r] = 0.f;
#pragma unroll
        for (int di = 0; di < 4; ++di) o[mi][di][r] = 0.f;
      }

    auto stage = [&](int buf, int kt) {
      const char* kb = kh + (size_t)kt * 8192;
      const char* vb = vh + (size_t)kt * 128;
#pragma unroll
      for (int i = 0; i < 4; ++i) {
        const int idx = wid * 4 + i;
        if (idx < 8) {
          load_lds16(kb + idx * 1024 + soK, (char*)&Kl[buf][0] + idx * 1024);
        } else {
          const int j = idx - 8;
          load_lds16(vb + (size_t)(j * 8 + vrow) * (Tc * 2) + vcol,
                     (char*)&Vl[buf][0] + j * 1024);
        }
      }
    };

    stage(0, 0);
    __syncthreads();
    int cur = 0;
    for (int kt = 0; kt <= ktB; ++kt) {
      if (kt < ktB) stage(cur ^ 1, kt + 1);
      if (kt <= ktW) {
        const char* Kb = (const char*)&Kl[cur][0];
        bf16x8 kf[4][2];
#pragma unroll
        for (int ni = 0; ni < 4; ++ni)
#pragma unroll
          for (int kk = 0; kk < 2; ++kk)
            kf[ni][kk] = *(const bf16x8*)(Kb + (ni * 16 + c) * 128 +
                                          (((kk << 6) | (g << 4)) ^ rsw));
        f32x4 s[2][4];
#pragma unroll
        for (int mi = 0; mi < 2; ++mi)
#pragma unroll
          for (int ni = 0; ni < 4; ++ni)
#pragma unroll
            for (int r = 0; r < 4; ++r) s[mi][ni][r] = 0.f;
        __builtin_amdgcn_s_setprio(1);
#pragma unroll
        for (int kk = 0; kk < 2; ++kk)
#pragma unroll
          for (int mi = 0; mi < 2; ++mi)
#pragma unroll
            for (int ni = 0; ni < 4; ++ni)
              s[mi][ni] = __builtin_amdgcn_mfma_f32_16x16x32_bf16(qf[mi][kk], kf[ni][kk],
                                                                  s[mi][ni], 0, 0, 0);
        __builtin_amdgcn_s_setprio(0);

        if (kt == ktW) {
#pragma unroll
          for (int mi = 0; mi < 2; ++mi)
#pragma unroll
            for (int ni = 0; ni < 4; ++ni)
#pragma unroll
              for (int r = 0; r < 4; ++r) {
                const int row = row0 + mi * 16 + g * 4 + r;
                const int col = kt * 64 + ni * 16 + c;
                if (col > row) s[mi][ni][r] = -1e30f;
              }
        }

        float pm[2][4];
        int need = 0;
#pragma unroll
        for (int mi = 0; mi < 2; ++mi)
#pragma unroll
          for (int r = 0; r < 4; ++r) {
            pm[mi][r] =
                fmaxf(fmaxf(s[mi][0][r], s[mi][1][r]), fmaxf(s[mi][2][r], s[mi][3][r]));
            need |= (pm[mi][r] > m_[mi][r] + 8.f) ? 1 : 0;
          }
        if (__any(need)) {
#pragma unroll
          for (int mi = 0; mi < 2; ++mi)
#pragma unroll
            for (int r = 0; r < 4; ++r) {
              float mx = pm[mi][r];
#pragma unroll
              for (int msk = 1; msk < 16; msk <<= 1) mx = fmaxf(mx, __shfl_xor(mx, msk));
              const float mn = fmaxf(m_[mi][r], mx);
              const float al = __expf(m_[mi][r] - mn);
              m_[mi][r] = mn;
              ls[mi][r] *= al;
#pragma unroll
              for (int di = 0; di < 4; ++di) o[mi][di][r] *= al;
            }
        }
#pragma unroll
        for (int mi = 0; mi < 2; ++mi)
#pragma unroll
          for (int r = 0; r < 4; ++r) {
            float ps = 0.f;
#pragma unroll
            for (int ni = 0; ni < 4; ++ni) {
              const float pv = __expf(s[mi][ni][r] - m_[mi][r]);
              ps += pv;
              P[wid][mi * 16 + g * 4 + r][ni * 16 + c] = (bf16)pv;
            }
            ls[mi][r] += ps;
          }
        asm volatile("s_waitcnt lgkmcnt(0)" ::: "memory");
        __builtin_amdgcn_sched_barrier(0);

        bf16x8 pf[2][2];
#pragma unroll
        for (int mi = 0; mi < 2; ++mi)
#pragma unroll
          for (int kk = 0; kk < 2; ++kk)
            pf[mi][kk] = *(const bf16x8*)&P[wid][mi * 16 + c][kk * 32 + g * 8];
        const char* Vb = (const char*)&Vl[cur][0];
#pragma unroll
        for (int di = 0; di < 4; ++di) {
          bf16x8 vf0 = *(const bf16x8*)(Vb + (di * 16 + c) * 128 + ((g << 4) ^ rsw));
          bf16x8 vf1 =
              *(const bf16x8*)(Vb + (di * 16 + c) * 128 + (((1 << 6) | (g << 4)) ^ rsw));
          __builtin_amdgcn_s_setprio(1);
#pragma unroll
          for (int mi = 0; mi < 2; ++mi) {
            o[mi][di] = __builtin_amdgcn_mfma_f32_16x16x32_bf16(pf[mi][0], vf0, o[mi][di], 0, 0, 0);
            o[mi][di] = __builtin_amdgcn_mfma_f32_16x16x32_bf16(pf[mi][1], vf1, o[mi][di], 0, 0, 0);
          }
          __builtin_amdgcn_s_setprio(0);
        }
      }
      __syncthreads();
      cur ^= 1;
    }

#pragma unroll
    for (int mi = 0; mi < 2; ++mi)
#pragma unroll
      for (int r = 0; r < 4; ++r) {
        float l = ls[mi][r];
#pragma unroll
        for (int msk = 1; msk < 16; msk <<= 1) l += __shfl_xor(l, msk);
        const float inv = 1.f / l;
        const int t = row0 + mi * 16 + g * 4 + r;
#pragma unroll
        for (int di = 0; di < 4; ++di)
          ctx[((size_t)(b * Tc + t)) * Dc + h * 64 + di * 16 + c] =
              (bf16)(o[mi][di][r] * inv);
      }
  }
}

// ---------------- launch ----------------
extern "C" void kernel_launch(void* const* d_in, const int* in_sizes, int n_in,
                              void* d_out, int out_size, void* d_ws, size_t ws_size,
                              hipStream_t stream) {
  (void)in_sizes; (void)n_in; (void)out_size; (void)ws_size;
  const float* x      = (const float*)d_in[0];
  const float* ln1_g  = (const float*)d_in[1];
  const float* ln1_b  = (const float*)d_in[2];
  const float* wq     = (const float*)d_in[3];
  const float* wk     = (const float*)d_in[4];
  const float* wv     = (const float*)d_in[5];
  const float* w_proj = (const float*)d_in[6];
  const float* b_proj = (const float*)d_in[7];
  const float* ln2_g  = (const float*)d_in[8];
  const float* ln2_b  = (const float*)d_in[9];
  const float* w1     = (const float*)d_in[10];
  const float* b1     = (const float*)d_in[11];
  const float* w2     = (const float*)d_in[12];
  const float* b2     = (const float*)d_in[13];
  float* out = (float*)d_out;
  char* ws = (char*)d_ws;

  bf16* qbuf   = (bf16*)(ws + 0);
  bf16* kbuf   = (bf16*)(ws + 16777216);
  bf16* vtbuf  = (bf16*)(ws + 33554432);
  bf16* ctxbuf = (bf16*)(ws + 50331648);
  bf16* wqkvT  = (bf16*)(ws + 67108864);
  bf16* hbuf   = (bf16*)(ws + 0);  // aliases q/k/vt/ctx, dead by FFN1
  bf16* wprojT = (bf16*)(ws + 73400320);
  bf16* w1T    = (bf16*)(ws + 75497472);
  bf16* w2T    = (bf16*)(ws + 83886080);
  bf16* xn     = (bf16*)(ws + 92274688);
  float* x1buf = (float*)(ws + 109051904);

  repack_qkv_kernel<<<dim3(16, 48), dim3(64, 4), 0, stream>>>(wq, wk, wv, wqkvT);
  transpose_to_bf16_kernel<<<dim3(16, 16), dim3(64, 4), 0, stream>>>(w_proj, wprojT, 1024, 1024);
  transpose_to_bf16_kernel<<<dim3(16, 64), dim3(64, 4), 0, stream>>>(w1, w1T, 1024, 4096);
  transpose_to_bf16_kernel<<<dim3(64, 16), dim3(64, 4), 0, stream>>>(w2, w2T, 4096, 1024);

  ln_kernel<<<Mrows, 256, 0, stream>>>(x, ln1_g, ln1_b, xn);
  gemm4p_kernel<0, 1024, 256><<<dim3(32, 12), 512, 0, stream>>>(
      xn, wqkvT, nullptr, nullptr, nullptr, nullptr, qbuf, kbuf, vtbuf);
  attn_kernel<<<512, 256, 0, stream>>>(qbuf, kbuf, vtbuf, ctxbuf);
  gemm4p_kernel<1, 1024, 128><<<dim3(32, 8), 512, 0, stream>>>(
      ctxbuf, wprojT, b_proj, x, x1buf, nullptr, nullptr, nullptr, nullptr);
  ln_kernel<<<Mrows, 256, 0, stream>>>(x1buf, ln2_g, ln2_b, xn);
  gemm4p_kernel<2, 1024, 256><<<dim3(32, 16), 512, 0, stream>>>(
      xn, w1T, b1, nullptr, nullptr, hbuf, nullptr, nullptr, nullptr);
  gemm4p_kernel<3, 4096, 128><<<dim3(32, 8), 512, 0, stream>>>(
      hbuf, w2T, b2, x1buf, out, nullptr, nullptr, nullptr, nullptr);
}

// Round 8
// 385.141 us; speedup vs baseline: 1.1368x; 1.1368x over previous
//
#include <hip/hip_runtime.h>

typedef __bf16 bf16;
typedef __attribute__((ext_vector_type(8))) __bf16 bf16x8;
typedef __attribute__((ext_vector_type(4))) __bf16 bf16x4;
typedef __attribute__((ext_vector_type(4))) float f32x4;

static constexpr int Bc = 4, Tc = 2048, Dc = 1024, Hc = 16, HSc = 64, DFF = 4096;
static constexpr int Mrows = Bc * Tc;  // 8192

#define DEV __device__ __forceinline__

DEV void load_lds16(const void* g, void* l) {
  __builtin_amdgcn_global_load_lds(
      (const __attribute__((address_space(1))) void*)g,
      (__attribute__((address_space(3))) void*)l, 16, 0, 0);
}

// ---------------- weight repack: wq/wk/wv [H,D,HS] -> WqkvT [3072(n)][1024(k=d)] bf16
__global__ void repack_qkv_kernel(const float* __restrict__ wq,
                                  const float* __restrict__ wk,
                                  const float* __restrict__ wv,
                                  bf16* __restrict__ dst) {
  __shared__ float tile[64][65];
  const int dblk = blockIdx.x;
  const int z = blockIdx.y;
  const int w = z >> 4, h = z & 15;
  const float* src = (w == 0 ? wq : (w == 1 ? wk : wv)) + (size_t)h * Dc * HSc;
  const int tx = threadIdx.x, ty = threadIdx.y;
#pragma unroll
  for (int i = 0; i < 16; ++i)
    tile[ty + i * 4][tx] = src[(size_t)(dblk * 64 + ty + i * 4) * HSc + tx];
  __syncthreads();
#pragma unroll
  for (int i = 0; i < 16; ++i) {
    const int s = ty + i * 4;
    dst[((size_t)w * 1024 + h * 64 + s) * Dc + dblk * 64 + tx] = (bf16)tile[tx][s];
  }
}

// ---------------- generic [R][C] f32 -> [C][R] bf16 transpose
__global__ void transpose_to_bf16_kernel(const float* __restrict__ src,
                                         bf16* __restrict__ dst, int R, int C) {
  __shared__ float tile[64][65];
  const int r0 = blockIdx.x * 64, c0 = blockIdx.y * 64;
  const int tx = threadIdx.x, ty = threadIdx.y;
#pragma unroll
  for (int i = 0; i < 16; ++i)
    tile[ty + i * 4][tx] = src[(size_t)(r0 + ty + i * 4) * C + c0 + tx];
  __syncthreads();
#pragma unroll
  for (int i = 0; i < 16; ++i)
    dst[(size_t)(c0 + ty + i * 4) * R + r0 + tx] = (bf16)tile[tx][ty + i * 4];
}

// ---------------- LayerNorm row kernel: f32 in -> bf16 out
__global__ __launch_bounds__(256) void ln_kernel(const float* __restrict__ x,
                                                 const float* __restrict__ gam,
                                                 const float* __restrict__ bet,
                                                 bf16* __restrict__ out) {
  const int row = blockIdx.x;
  const int t = threadIdx.x;
  const float4 v = ((const float4*)(x + (size_t)row * Dc))[t];
  float s = v.x + v.y + v.z + v.w;
  float s2 = v.x * v.x + v.y * v.y + v.z * v.z + v.w * v.w;
#pragma unroll
  for (int m = 1; m < 64; m <<= 1) {
    s += __shfl_xor(s, m);
    s2 += __shfl_xor(s2, m);
  }
  __shared__ float red[8];
  const int wid = t >> 6;
  if ((t & 63) == 0) { red[wid * 2] = s; red[wid * 2 + 1] = s2; }
  __syncthreads();
  s = red[0] + red[2] + red[4] + red[6];
  s2 = red[1] + red[3] + red[5] + red[7];
  const float mean = s * (1.f / Dc);
  const float var = s2 * (1.f / Dc) - mean * mean;
  const float rstd = rsqrtf(var + 1e-5f);
  const float4 gv = ((const float4*)gam)[t];
  const float4 bv = ((const float4*)bet)[t];
  bf16x4 o;
  o[0] = (bf16)((v.x - mean) * rstd * gv.x + bv.x);
  o[1] = (bf16)((v.y - mean) * rstd * gv.y + bv.y);
  o[2] = (bf16)((v.z - mean) * rstd * gv.z + bv.z);
  o[3] = (bf16)((v.w - mean) * rstd * gv.w + bv.w);
  *(bf16x4*)(out + (size_t)row * Dc + t * 4) = o;
}

// ---------------- GEMM v5: m201-style 8-phase schedule, BM=256, BK=64.
// kslot-major LDS regions [side][ks][rows x 32cols]: 64B rows -> frag ds_read_b128
// is a contiguous 1KB stripe (conflict-free, no swizzle, linear gload dest).
// BN=256: 8 waves 2Mx4N (per-wave 128x64), 4 phases/K-tile, vmcnt(6) gate.
// BN=128: 8 waves 4Mx2N (per-wave 64x64),  2 phases/K-tile, vmcnt(3) gate.
// Each phase stages exactly the region freed by the previous phase (tile t+1/t+2).
template <int MODE, int KTOT, int BN>
__global__ __launch_bounds__(512, 1) void gemm8p_kernel(
    const bf16* __restrict__ A, const bf16* __restrict__ BT,
    const float* __restrict__ bias, const float* __restrict__ resid,
    float* __restrict__ outf, bf16* __restrict__ outb,
    bf16* __restrict__ qo, bf16* __restrict__ ko, bf16* __restrict__ vto) {
  constexpr int NT = KTOT / 64;
  constexpr int NSTR = (MODE == 2) ? 4096 : 1024;
  constexpr int WMD = (BN == 256) ? 2 : 4;  // waves along M
  constexpr int MW = 256 / WMD;             // per-wave rows: 128 or 64
  constexpr int NAF = MW / 16;              // 8 or 4
  constexpr int NBI = BN / 128;             // gloads per B region: 2 or 1

  __shared__ __attribute__((aligned(16))) bf16 As[2][2][256 * 32];
  __shared__ __attribute__((aligned(16))) bf16 Bs[2][2][BN * 32];

  const int tid = threadIdx.x;
  const int wid = tid >> 6, lane = tid & 63;
  const int g = (lane >> 4) & 3, c = lane & 15;
  const int wmi = (BN == 256) ? (wid >> 2) : (wid >> 1);
  const int wni = (BN == 256) ? (wid & 3) : (wid & 1);
  const int bm = blockIdx.x, bn = blockIdx.y;

  f32x4 acc[NAF][4];
#pragma unroll
  for (int i = 0; i < NAF; ++i)
#pragma unroll
    for (int j = 0; j < 4; ++j)
#pragma unroll
      for (int r = 0; r < 4; ++r) acc[i][j][r] = 0.f;

  const char* Agl = (const char*)A;
  const char* Bgl = (const char*)BT;
  const int grow = tid >> 2;       // 0..127
  const int gcol = (tid & 3) * 8;  // elem offset within 32-col kslot

  auto stageA = [&](int side, int ks, int kt) {
#pragma unroll
    for (int a = 0; a < 2; ++a)
      load_lds16(
          Agl + ((size_t)(bm * 256 + a * 128 + grow) * KTOT + kt * 64 + ks * 32 + gcol) * 2,
          (char*)&As[side][ks][0] + a * 8192 + tid * 16);
  };
  auto stageB = [&](int side, int ks, int kt) {
#pragma unroll
    for (int b = 0; b < NBI; ++b)
      load_lds16(
          Bgl + ((size_t)(bn * BN + b * 128 + grow) * KTOT + kt * 64 + ks * 32 + gcol) * 2,
          (char*)&Bs[side][ks][0] + b * 8192 + tid * 16);
  };

  const int aoff = (wmi * MW + c) * 64 + g * 16;  // byte offset of frag 0 in A region
  const int boff = (wni * 64 + c) * 64 + g * 16;  // byte offset of frag 0 in B region

  // prologue: tile 0 full; tile 1 minus its last region (staged in t=0's P1)
  if (BN == 256) {
    stageB(0, 0, 0); stageA(0, 0, 0); stageB(0, 1, 0); stageA(0, 1, 0);
    stageB(1, 0, 1); stageA(1, 0, 1); stageB(1, 1, 1);
    asm volatile("s_waitcnt vmcnt(6)" ::: "memory");
  } else {
    stageA(0, 0, 0); stageB(0, 0, 0); stageA(0, 1, 0); stageB(0, 1, 0);
    stageA(1, 0, 1); stageB(1, 0, 1);
    asm volatile("s_waitcnt vmcnt(3)" ::: "memory");
  }
  __builtin_amdgcn_s_barrier();

  for (int t = 0; t < NT; ++t) {
    const int s = t & 1, ns = s ^ 1;
    const char* Ab0 = (const char*)&As[s][0][0] + aoff;
    const char* Ab1 = (const char*)&As[s][1][0] + aoff;
    const char* Bb0 = (const char*)&Bs[s][0][0] + boff;
    const char* Bb1 = (const char*)&Bs[s][1][0] + boff;
    bf16x8 af[4], bfr[4];

    if (BN == 256) {
      // ---- P1: frags A[0-3][ks0], B[ks0]; stage A[ks1]@t+1
#pragma unroll
      for (int f = 0; f < 4; ++f) af[f] = *(const bf16x8*)(Ab0 + f * 1024);
#pragma unroll
      for (int j = 0; j < 4; ++j) bfr[j] = *(const bf16x8*)(Bb0 + j * 1024);
      if (t + 1 < NT) stageA(ns, 1, t + 1);
      __builtin_amdgcn_s_barrier();
      asm volatile("s_waitcnt lgkmcnt(0)" ::: "memory");
      __builtin_amdgcn_sched_barrier(0);
      __builtin_amdgcn_s_setprio(1);
#pragma unroll
      for (int f = 0; f < 4; ++f)
#pragma unroll
        for (int j = 0; j < 4; ++j)
          acc[f][j] = __builtin_amdgcn_mfma_f32_16x16x32_bf16(af[f], bfr[j], acc[f][j], 0, 0, 0);
      __builtin_amdgcn_s_setprio(0);
      __builtin_amdgcn_s_barrier();
      // ---- P2: frags A[4-7][ks0]; stage B[ks0]@t+2
#pragma unroll
      for (int f = 0; f < 4; ++f) af[f] = *(const bf16x8*)(Ab0 + (4 + f) * 1024);
      if (t + 2 < NT) stageB(s, 0, t + 2);
      __builtin_amdgcn_s_barrier();
      asm volatile("s_waitcnt lgkmcnt(0)" ::: "memory");
      __builtin_amdgcn_sched_barrier(0);
      __builtin_amdgcn_s_setprio(1);
#pragma unroll
      for (int f = 0; f < 4; ++f)
#pragma unroll
        for (int j = 0; j < 4; ++j)
          acc[4 + f][j] =
              __builtin_amdgcn_mfma_f32_16x16x32_bf16(af[f], bfr[j], acc[4 + f][j], 0, 0, 0);
      __builtin_amdgcn_s_setprio(0);
      __builtin_amdgcn_s_barrier();
      // ---- P3: frags A[0-3][ks1], B[ks1]; stage A[ks0]@t+2
#pragma unroll
      for (int f = 0; f < 4; ++f) af[f] = *(const bf16x8*)(Ab1 + f * 1024);
#pragma unroll
      for (int j = 0; j < 4; ++j) bfr[j] = *(const bf16x8*)(Bb1 + j * 1024);
      if (t + 2 < NT) stageA(s, 0, t + 2);
      __builtin_amdgcn_s_barrier();
      asm volatile("s_waitcnt lgkmcnt(0)" ::: "memory");
      __builtin_amdgcn_sched_barrier(0);
      __builtin_amdgcn_s_setprio(1);
#pragma unroll
      for (int f = 0; f < 4; ++f)
#pragma unroll
        for (int j = 0; j < 4; ++j)
          acc[f][j] = __builtin_amdgcn_mfma_f32_16x16x32_bf16(af[f], bfr[j], acc[f][j], 0, 0, 0);
      __builtin_amdgcn_s_setprio(0);
      __builtin_amdgcn_s_barrier();
      // ---- P4: frags A[4-7][ks1]; stage B[ks1]@t+2; tile-end counted gate
#pragma unroll
      for (int f = 0; f < 4; ++f) af[f] = *(const bf16x8*)(Ab1 + (4 + f) * 1024);
      if (t + 2 < NT) stageB(s, 1, t + 2);
      __builtin_amdgcn_s_barrier();
      asm volatile("s_waitcnt lgkmcnt(0)" ::: "memory");
      __builtin_amdgcn_sched_barrier(0);
      __builtin_amdgcn_s_setprio(1);
#pragma unroll
      for (int f = 0; f < 4; ++f)
#pragma unroll
        for (int j = 0; j < 4; ++j)
          acc[4 + f][j] =
              __builtin_amdgcn_mfma_f32_16x16x32_bf16(af[f], bfr[j], acc[4 + f][j], 0, 0, 0);
      __builtin_amdgcn_s_setprio(0);
      if (t + 2 < NT) {
        asm volatile("s_waitcnt vmcnt(6)" ::: "memory");  // tile t+1 landed; 3 regions in flight
      } else {
        asm volatile("s_waitcnt vmcnt(0)" ::: "memory");
      }
      __builtin_amdgcn_s_barrier();
    } else {
      // ---- P1 (ks0): frags A[0-3][ks0], B[ks0]; stage ks1@t+1
#pragma unroll
      for (int f = 0; f < 4; ++f) af[f] = *(const bf16x8*)(Ab0 + f * 1024);
#pragma unroll
      for (int j = 0; j < 4; ++j) bfr[j] = *(const bf16x8*)(Bb0 + j * 1024);
      if (t + 1 < NT) { stageA(ns, 1, t + 1); stageB(ns, 1, t + 1); }
      __builtin_amdgcn_s_barrier();
      asm volatile("s_waitcnt lgkmcnt(0)" ::: "memory");
      __builtin_amdgcn_sched_barrier(0);
      __builtin_amdgcn_s_setprio(1);
#pragma unroll
      for (int f = 0; f < 4; ++f)
#pragma unroll
        for (int j = 0; j < 4; ++j)
          acc[f][j] = __builtin_amdgcn_mfma_f32_16x16x32_bf16(af[f], bfr[j], acc[f][j], 0, 0, 0);
      __builtin_amdgcn_s_setprio(0);
      __builtin_amdgcn_s_barrier();
      // ---- P2 (ks1): frags A[ks1], B[ks1]; stage ks0@t+2; tile-end counted gate
#pragma unroll
      for (int f = 0; f < 4; ++f) af[f] = *(const bf16x8*)(Ab1 + f * 1024);
#pragma unroll
      for (int j = 0; j < 4; ++j) bfr[j] = *(const bf16x8*)(Bb1 + j * 1024);
      if (t + 2 < NT) { stageA(s, 0, t + 2); stageB(s, 0, t + 2); }
      __builtin_amdgcn_s_barrier();
      asm volatile("s_waitcnt lgkmcnt(0)" ::: "memory");
      __builtin_amdgcn_sched_barrier(0);
      __builtin_amdgcn_s_setprio(1);
#pragma unroll
      for (int f = 0; f < 4; ++f)
#pragma unroll
        for (int j = 0; j < 4; ++j)
          acc[f][j] = __builtin_amdgcn_mfma_f32_16x16x32_bf16(af[f], bfr[j], acc[f][j], 0, 0, 0);
      __builtin_amdgcn_s_setprio(0);
      if (t + 2 < NT) {
        asm volatile("s_waitcnt vmcnt(3)" ::: "memory");  // tile t+1 landed; 1 region in flight
      } else {
        asm volatile("s_waitcnt vmcnt(0)" ::: "memory");
      }
      __builtin_amdgcn_s_barrier();
    }
  }

  // epilogue: rows m0 = bm*256+wmi*MW+fr*16+g*4 (+r), col n = bn*BN+wni*64+nf*16+c
#pragma unroll
  for (int nf = 0; nf < 4; ++nf) {
    const int n = bn * BN + wni * 64 + nf * 16 + c;
    float bi = 0.f;
    if (MODE != 0) bi = bias[n];
#pragma unroll
    for (int fr = 0; fr < NAF; ++fr) {
      const int m0 = bm * 256 + wmi * MW + fr * 16 + g * 4;
      if (MODE == 0) {
        const int w = n >> 10, n1 = n & 1023, h = n1 >> 6, sidx = n1 & 63;
        const int b2 = m0 >> 11, t0 = m0 & 2047;
        if (w == 0) {
#pragma unroll
          for (int r = 0; r < 4; ++r)
            qo[(size_t)(b2 * Hc + h) * (Tc * HSc) + (size_t)(t0 + r) * HSc + sidx] =
                (bf16)(acc[fr][nf][r] * 0.125f);
        } else if (w == 1) {
#pragma unroll
          for (int r = 0; r < 4; ++r)
            ko[(size_t)(b2 * Hc + h) * (Tc * HSc) + (size_t)(t0 + r) * HSc + sidx] =
                (bf16)acc[fr][nf][r];
        } else {
          bf16x4 pk;
#pragma unroll
          for (int r = 0; r < 4; ++r) pk[r] = (bf16)acc[fr][nf][r];
          *(bf16x4*)&vto[((size_t)(b2 * Hc + h) * HSc + sidx) * Tc + t0] = pk;
        }
      } else if (MODE == 1 || MODE == 3) {
#pragma unroll
        for (int r = 0; r < 4; ++r) {
          const size_t idx = (size_t)(m0 + r) * NSTR + n;
          outf[idx] = acc[fr][nf][r] + bi + resid[idx];
        }
      } else {
#pragma unroll
        for (int r = 0; r < 4; ++r)
          outb[(size_t)(m0 + r) * NSTR + n] = (bf16)fmaxf(acc[fr][nf][r] + bi, 0.f);
      }
    }
  }
}

// ---------------- causal flash attention (unchanged from R3)
__global__ __launch_bounds__(256, 2) void attn_kernel(const bf16* __restrict__ q,
                                                      const bf16* __restrict__ k,
                                                      const bf16* __restrict__ vt,
                                                      bf16* __restrict__ ctx) {
  __shared__ __attribute__((aligned(16))) bf16 Kl[2][4096];
  __shared__ __attribute__((aligned(16))) bf16 Vl[2][4096];
  __shared__ __attribute__((aligned(16))) bf16 P[4][32][72];
  const int d0 = blockIdx.x;
  const int L = (d0 & 7) * 64 + (d0 >> 3);
  const int bh = L >> 3, p = L & 7;
  const int tid = threadIdx.x;
  const int wid = tid >> 6, lane = tid & 63;
  const int g = lane >> 4, c = lane & 15;
  const bf16* qh = q + (size_t)bh * Tc * HSc;
  const char* kh = (const char*)(k + (size_t)bh * Tc * HSc);
  const char* vh = (const char*)(vt + (size_t)bh * HSc * Tc);
  const int b = bh >> 4, h = bh & 15;

  const int sw = ((lane >> 3) & 7) << 4;
  const int soK = (lane * 16) ^ sw;
  const int vrow = lane >> 3;
  const int vcol = ((lane & 7) * 16) ^ sw;
  const int rsw = (c & 7) << 4;

  for (int g2 = 0; g2 < 2; ++g2) {
    const int grp = g2 ? p : 15 - p;
    const int ktB = 2 * grp + 1;
    const int ktW = 2 * grp + (wid >> 1);
    const int row0 = grp * 128 + wid * 32;
    const bf16* qb = qh + (size_t)row0 * HSc;

    bf16x8 qf[2][2];
#pragma unroll
    for (int mi = 0; mi < 2; ++mi)
#pragma unroll
      for (int kk = 0; kk < 2; ++kk)
        qf[mi][kk] = *(const bf16x8*)&qb[(size_t)(mi * 16 + c) * HSc + kk * 32 + g * 8];

    f32x4 o[2][4];
    float m_[2][4], ls[2][4];
#pragma unroll
    for (int mi = 0; mi < 2; ++mi)
#pragma unroll
      for (int r = 0; r < 4; ++r) {
        m_[mi][r] = -1e30f;
        ls[mi][r] = 0.f;
#pragma unroll
        for (int di = 0; di < 4; ++di) o[mi][di][r] = 0.f;
      }

    auto stage = [&](int buf, int kt) {
      const char* kb = kh + (size_t)kt * 8192;
      const char* vb = vh + (size_t)kt * 128;
#pragma unroll
      for (int i = 0; i < 4; ++i) {
        const int idx = wid * 4 + i;
        if (idx < 8) {
          load_lds16(kb + idx * 1024 + soK, (char*)&Kl[buf][0] + idx * 1024);
        } else {
          const int j = idx - 8;
          load_lds16(vb + (size_t)(j * 8 + vrow) * (Tc * 2) + vcol,
                     (char*)&Vl[buf][0] + j * 1024);
        }
      }
    };

    stage(0, 0);
    __syncthreads();
    int cur = 0;
    for (int kt = 0; kt <= ktB; ++kt) {
      if (kt < ktB) stage(cur ^ 1, kt + 1);
      if (kt <= ktW) {
        const char* Kb = (const char*)&Kl[cur][0];
        bf16x8 kf[4][2];
#pragma unroll
        for (int ni = 0; ni < 4; ++ni)
#pragma unroll
          for (int kk = 0; kk < 2; ++kk)
            kf[ni][kk] = *(const bf16x8*)(Kb + (ni * 16 + c) * 128 +
                                          (((kk << 6) | (g << 4)) ^ rsw));
        f32x4 s[2][4];
#pragma unroll
        for (int mi = 0; mi < 2; ++mi)
#pragma unroll
          for (int ni = 0; ni < 4; ++ni)
#pragma unroll
            for (int r = 0; r < 4; ++r) s[mi][ni][r] = 0.f;
        __builtin_amdgcn_s_setprio(1);
#pragma unroll
        for (int kk = 0; kk < 2; ++kk)
#pragma unroll
          for (int mi = 0; mi < 2; ++mi)
#pragma unroll
            for (int ni = 0; ni < 4; ++ni)
              s[mi][ni] = __builtin_amdgcn_mfma_f32_16x16x32_bf16(qf[mi][kk], kf[ni][kk],
                                                                  s[mi][ni], 0, 0, 0);
        __builtin_amdgcn_s_setprio(0);

        if (kt == ktW) {
#pragma unroll
          for (int mi = 0; mi < 2; ++mi)
#pragma unroll
            for (int ni = 0; ni < 4; ++ni)
#pragma unroll
              for (int r = 0; r < 4; ++r) {
                const int row = row0 + mi * 16 + g * 4 + r;
                const int col = kt * 64 + ni * 16 + c;
                if (col > row) s[mi][ni][r] = -1e30f;
              }
        }

        float pm[2][4];
        int need = 0;
#pragma unroll
        for (int mi = 0; mi < 2; ++mi)
#pragma unroll
          for (int r = 0; r < 4; ++r) {
            pm[mi][r] =
                fmaxf(fmaxf(s[mi][0][r], s[mi][1][r]), fmaxf(s[mi][2][r], s[mi][3][r]));
            need |= (pm[mi][r] > m_[mi][r] + 8.f) ? 1 : 0;
          }
        if (__any(need)) {
#pragma unroll
          for (int mi = 0; mi < 2; ++mi)
#pragma unroll
            for (int r = 0; r < 4; ++r) {
              float mx = pm[mi][r];
#pragma unroll
              for (int msk = 1; msk < 16; msk <<= 1) mx = fmaxf(mx, __shfl_xor(mx, msk));
              const float mn = fmaxf(m_[mi][r], mx);
              const float al = __expf(m_[mi][r] - mn);
              m_[mi][r] = mn;
              ls[mi][r] *= al;
#pragma unroll
              for (int di = 0; di < 4; ++di) o[mi][di][r] *= al;
            }
        }
#pragma unroll
        for (int mi = 0; mi < 2; ++mi)
#pragma unroll
          for (int r = 0; r < 4; ++r) {
            float ps = 0.f;
#pragma unroll
            for (int ni = 0; ni < 4; ++ni) {
              const float pv = __expf(s[mi][ni][r] - m_[mi][r]);
              ps += pv;
              P[wid][mi * 16 + g * 4 + r][ni * 16 + c] = (bf16)pv;
            }
            ls[mi][r] += ps;
          }
        asm volatile("s_waitcnt lgkmcnt(0)" ::: "memory");
        __builtin_amdgcn_sched_barrier(0);

        bf16x8 pf[2][2];
#pragma unroll
        for (int mi = 0; mi < 2; ++mi)
#pragma unroll
          for (int kk = 0; kk < 2; ++kk)
            pf[mi][kk] = *(const bf16x8*)&P[wid][mi * 16 + c][kk * 32 + g * 8];
        const char* Vb = (const char*)&Vl[cur][0];
#pragma unroll
        for (int di = 0; di < 4; ++di) {
          bf16x8 vf0 = *(const bf16x8*)(Vb + (di * 16 + c) * 128 + ((g << 4) ^ rsw));
          bf16x8 vf1 =
              *(const bf16x8*)(Vb + (di * 16 + c) * 128 + (((1 << 6) | (g << 4)) ^ rsw));
          __builtin_amdgcn_s_setprio(1);
#pragma unroll
          for (int mi = 0; mi < 2; ++mi) {
            o[mi][di] = __builtin_amdgcn_mfma_f32_16x16x32_bf16(pf[mi][0], vf0, o[mi][di], 0, 0, 0);
            o[mi][di] = __builtin_amdgcn_mfma_f32_16x16x32_bf16(pf[mi][1], vf1, o[mi][di], 0, 0, 0);
          }
          __builtin_amdgcn_s_setprio(0);
        }
      }
      __syncthreads();
      cur ^= 1;
    }

#pragma unroll
    for (int mi = 0; mi < 2; ++mi)
#pragma unroll
      for (int r = 0; r < 4; ++r) {
        float l = ls[mi][r];
#pragma unroll
        for (int msk = 1; msk < 16; msk <<= 1) l += __shfl_xor(l, msk);
        const float inv = 1.f / l;
        const int t = row0 + mi * 16 + g * 4 + r;
#pragma unroll
        for (int di = 0; di < 4; ++di)
          ctx[((size_t)(b * Tc + t)) * Dc + h * 64 + di * 16 + c] =
              (bf16)(o[mi][di][r] * inv);
      }
  }
}

// ---------------- launch ----------------
extern "C" void kernel_launch(void* const* d_in, const int* in_sizes, int n_in,
                              void* d_out, int out_size, void* d_ws, size_t ws_size,
                              hipStream_t stream) {
  (void)in_sizes; (void)n_in; (void)out_size; (void)ws_size;
  const float* x      = (const float*)d_in[0];
  const float* ln1_g  = (const float*)d_in[1];
  const float* ln1_b  = (const float*)d_in[2];
  const float* wq     = (const float*)d_in[3];
  const float* wk     = (const float*)d_in[4];
  const float* wv     = (const float*)d_in[5];
  const float* w_proj = (const float*)d_in[6];
  const float* b_proj = (const float*)d_in[7];
  const float* ln2_g  = (const float*)d_in[8];
  const float* ln2_b  = (const float*)d_in[9];
  const float* w1     = (const float*)d_in[10];
  const float* b1     = (const float*)d_in[11];
  const float* w2     = (const float*)d_in[12];
  const float* b2     = (const float*)d_in[13];
  float* out = (float*)d_out;
  char* ws = (char*)d_ws;

  bf16* qbuf   = (bf16*)(ws + 0);
  bf16* kbuf   = (bf16*)(ws + 16777216);
  bf16* vtbuf  = (bf16*)(ws + 33554432);
  bf16* ctxbuf = (bf16*)(ws + 50331648);
  bf16* wqkvT  = (bf16*)(ws + 67108864);
  bf16* hbuf   = (bf16*)(ws + 0);  // aliases q/k/vt/ctx, dead by FFN1
  bf16* wprojT = (bf16*)(ws + 73400320);
  bf16* w1T    = (bf16*)(ws + 75497472);
  bf16* w2T    = (bf16*)(ws + 83886080);
  bf16* xn     = (bf16*)(ws + 92274688);
  float* x1buf = (float*)(ws + 109051904);

  repack_qkv_kernel<<<dim3(16, 48), dim3(64, 4), 0, stream>>>(wq, wk, wv, wqkvT);
  transpose_to_bf16_kernel<<<dim3(16, 16), dim3(64, 4), 0, stream>>>(w_proj, wprojT, 1024, 1024);
  transpose_to_bf16_kernel<<<dim3(16, 64), dim3(64, 4), 0, stream>>>(w1, w1T, 1024, 4096);
  transpose_to_bf16_kernel<<<dim3(64, 16), dim3(64, 4), 0, stream>>>(w2, w2T, 4096, 1024);

  ln_kernel<<<Mrows, 256, 0, stream>>>(x, ln1_g, ln1_b, xn);
  gemm8p_kernel<0, 1024, 128><<<dim3(32, 24), 512, 0, stream>>>(
      xn, wqkvT, nullptr, nullptr, nullptr, nullptr, qbuf, kbuf, vtbuf);
  attn_kernel<<<512, 256, 0, stream>>>(qbuf, kbuf, vtbuf, ctxbuf);
  gemm8p_kernel<1, 1024, 128><<<dim3(32, 8), 512, 0, stream>>>(
      ctxbuf, wprojT, b_proj, x, x1buf, nullptr, nullptr, nullptr, nullptr);
  ln_kernel<<<Mrows, 256, 0, stream>>>(x1buf, ln2_g, ln2_b, xn);
  gemm8p_kernel<2, 1024, 256><<<dim3(32, 16), 512, 0, stream>>>(
      xn, w1T, b1, nullptr, nullptr, hbuf, nullptr, nullptr, nullptr);
  gemm8p_kernel<3, 4096, 128><<<dim3(32, 8), 512, 0, stream>>>(
      hbuf, w2T, b2, x1buf, out, nullptr, nullptr, nullptr, nullptr);
}

// Round 9
// 375.910 us; speedup vs baseline: 1.1647x; 1.0246x over previous
//
#include <hip/hip_runtime.h>

typedef __bf16 bf16;
typedef __attribute__((ext_vector_type(8))) __bf16 bf16x8;
typedef __attribute__((ext_vector_type(4))) __bf16 bf16x4;
typedef __attribute__((ext_vector_type(4))) float f32x4;

static constexpr int Bc = 4, Tc = 2048, Dc = 1024, Hc = 16, HSc = 64, DFF = 4096;
static constexpr int Mrows = Bc * Tc;  // 8192

#define DEV __device__ __forceinline__

DEV void load_lds16(const void* g, void* l) {
  __builtin_amdgcn_global_load_lds(
      (const __attribute__((address_space(1))) void*)g,
      (__attribute__((address_space(3))) void*)l, 16, 0, 0);
}

// ---------------- weight repack: wq/wk/wv [H,D,HS] -> WqkvT [3072(n)][1024(k=d)] bf16
__global__ void repack_qkv_kernel(const float* __restrict__ wq,
                                  const float* __restrict__ wk,
                                  const float* __restrict__ wv,
                                  bf16* __restrict__ dst) {
  __shared__ float tile[64][65];
  const int dblk = blockIdx.x;
  const int z = blockIdx.y;
  const int w = z >> 4, h = z & 15;
  const float* src = (w == 0 ? wq : (w == 1 ? wk : wv)) + (size_t)h * Dc * HSc;
  const int tx = threadIdx.x, ty = threadIdx.y;
#pragma unroll
  for (int i = 0; i < 16; ++i)
    tile[ty + i * 4][tx] = src[(size_t)(dblk * 64 + ty + i * 4) * HSc + tx];
  __syncthreads();
#pragma unroll
  for (int i = 0; i < 16; ++i) {
    const int s = ty + i * 4;
    dst[((size_t)w * 1024 + h * 64 + s) * Dc + dblk * 64 + tx] = (bf16)tile[tx][s];
  }
}

// ---------------- generic [R][C] f32 -> [C][R] bf16 transpose
__global__ void transpose_to_bf16_kernel(const float* __restrict__ src,
                                         bf16* __restrict__ dst, int R, int C) {
  __shared__ float tile[64][65];
  const int r0 = blockIdx.x * 64, c0 = blockIdx.y * 64;
  const int tx = threadIdx.x, ty = threadIdx.y;
#pragma unroll
  for (int i = 0; i < 16; ++i)
    tile[ty + i * 4][tx] = src[(size_t)(r0 + ty + i * 4) * C + c0 + tx];
  __syncthreads();
#pragma unroll
  for (int i = 0; i < 16; ++i)
    dst[(size_t)(c0 + ty + i * 4) * R + r0 + tx] = (bf16)tile[tx][ty + i * 4];
}

// ---------------- LayerNorm row kernel: f32 in -> bf16 out
__global__ __launch_bounds__(256) void ln_kernel(const float* __restrict__ x,
                                                 const float* __restrict__ gam,
                                                 const float* __restrict__ bet,
                                                 bf16* __restrict__ out) {
  const int row = blockIdx.x;
  const int t = threadIdx.x;
  const float4 v = ((const float4*)(x + (size_t)row * Dc))[t];
  float s = v.x + v.y + v.z + v.w;
  float s2 = v.x * v.x + v.y * v.y + v.z * v.z + v.w * v.w;
#pragma unroll
  for (int m = 1; m < 64; m <<= 1) {
    s += __shfl_xor(s, m);
    s2 += __shfl_xor(s2, m);
  }
  __shared__ float red[8];
  const int wid = t >> 6;
  if ((t & 63) == 0) { red[wid * 2] = s; red[wid * 2 + 1] = s2; }
  __syncthreads();
  s = red[0] + red[2] + red[4] + red[6];
  s2 = red[1] + red[3] + red[5] + red[7];
  const float mean = s * (1.f / Dc);
  const float var = s2 * (1.f / Dc) - mean * mean;
  const float rstd = rsqrtf(var + 1e-5f);
  const float4 gv = ((const float4*)gam)[t];
  const float4 bv = ((const float4*)bet)[t];
  bf16x4 o;
  o[0] = (bf16)((v.x - mean) * rstd * gv.x + bv.x);
  o[1] = (bf16)((v.y - mean) * rstd * gv.y + bv.y);
  o[2] = (bf16)((v.z - mean) * rstd * gv.z + bv.z);
  o[3] = (bf16)((v.w - mean) * rstd * gv.w + bv.w);
  *(bf16x4*)(out + (size_t)row * Dc + t * 4) = o;
}

// ---------------- GEMM v6: R8's phased schedule + (row>>1)&3 16B-unit XOR
// swizzle both-sides (fixes R8's 8-way conflict on 64B-row kslot regions:
// bank = 16*(row&1) + 4*(u ^ ((row>>1)&3)) -> 2-way, free per m136).
// BN=256: 8 waves 2Mx4N (per-wave 128x64), 4 phases/K-tile, vmcnt(6) gate.
// BN=128: 8 waves 4Mx2N (per-wave 64x64),  2 phases/K-tile, vmcnt(3) gate.
template <int MODE, int KTOT, int BN>
__global__ __launch_bounds__(512, 1) void gemm9p_kernel(
    const bf16* __restrict__ A, const bf16* __restrict__ BT,
    const float* __restrict__ bias, const float* __restrict__ resid,
    float* __restrict__ outf, bf16* __restrict__ outb,
    bf16* __restrict__ qo, bf16* __restrict__ ko, bf16* __restrict__ vto) {
  constexpr int NT = KTOT / 64;
  constexpr int NSTR = (MODE == 2) ? 4096 : 1024;
  constexpr int WMD = (BN == 256) ? 2 : 4;  // waves along M
  constexpr int MW = 256 / WMD;             // per-wave rows: 128 or 64
  constexpr int NAF = MW / 16;              // 8 or 4
  constexpr int NBI = BN / 128;             // gloads per B region: 2 or 1

  __shared__ __attribute__((aligned(16))) bf16 As[2][2][256 * 32];
  __shared__ __attribute__((aligned(16))) bf16 Bs[2][2][BN * 32];

  const int tid = threadIdx.x;
  const int wid = tid >> 6, lane = tid & 63;
  const int g = (lane >> 4) & 3, c = lane & 15;
  const int wmi = (BN == 256) ? (wid >> 2) : (wid >> 1);
  const int wni = (BN == 256) ? (wid & 3) : (wid & 1);
  const int bm = blockIdx.x, bn = blockIdx.y;

  f32x4 acc[NAF][4];
#pragma unroll
  for (int i = 0; i < NAF; ++i)
#pragma unroll
    for (int j = 0; j < 4; ++j)
#pragma unroll
      for (int r = 0; r < 4; ++r) acc[i][j][r] = 0.f;

  const char* Agl = (const char*)A;
  const char* Bgl = (const char*)BT;
  const int grow = tid >> 2;  // 0..127: LDS dest row within 8KB call
  // dest unit = tid&3 (linear, per gload_lds rule); source unit = dest ^ ((row>>1)&3)
  const int gsw = (((tid & 3) ^ ((tid >> 3) & 3)) << 4);

  auto stageA = [&](int side, int ks, int kt) {
#pragma unroll
    for (int a = 0; a < 2; ++a)
      load_lds16(
          Agl + ((size_t)(bm * 256 + a * 128 + grow) * KTOT + kt * 64 + ks * 32) * 2 + gsw,
          (char*)&As[side][ks][0] + a * 8192 + tid * 16);
  };
  auto stageB = [&](int side, int ks, int kt) {
#pragma unroll
    for (int b = 0; b < NBI; ++b)
      load_lds16(
          Bgl + ((size_t)(bn * BN + b * 128 + grow) * KTOT + kt * 64 + ks * 32) * 2 + gsw,
          (char*)&Bs[side][ks][0] + b * 8192 + tid * 16);
  };

  // frag-read byte offsets: row = (wave base + f*16 + c); (row>>1)&3 == (c>>1)&3
  const int rsw = ((c >> 1) & 3) << 4;
  const int aoff = (wmi * MW + c) * 64 + ((g * 16) ^ rsw);
  const int boff = (wni * 64 + c) * 64 + ((g * 16) ^ rsw);

  // prologue: tile 0 full; tile 1 minus its last region (staged in t=0's P1)
  if (BN == 256) {
    stageB(0, 0, 0); stageA(0, 0, 0); stageB(0, 1, 0); stageA(0, 1, 0);
    stageB(1, 0, 1); stageA(1, 0, 1); stageB(1, 1, 1);
    asm volatile("s_waitcnt vmcnt(6)" ::: "memory");
  } else {
    stageA(0, 0, 0); stageB(0, 0, 0); stageA(0, 1, 0); stageB(0, 1, 0);
    stageA(1, 0, 1); stageB(1, 0, 1);
    asm volatile("s_waitcnt vmcnt(3)" ::: "memory");
  }
  __builtin_amdgcn_s_barrier();

  for (int t = 0; t < NT; ++t) {
    const int s = t & 1, ns = s ^ 1;
    const char* Ab0 = (const char*)&As[s][0][0] + aoff;
    const char* Ab1 = (const char*)&As[s][1][0] + aoff;
    const char* Bb0 = (const char*)&Bs[s][0][0] + boff;
    const char* Bb1 = (const char*)&Bs[s][1][0] + boff;
    bf16x8 af[4], bfr[4];

    if (BN == 256) {
      // ---- P1: frags A[0-3][ks0], B[ks0]; stage A[ks1]@t+1
#pragma unroll
      for (int f = 0; f < 4; ++f) af[f] = *(const bf16x8*)(Ab0 + f * 1024);
#pragma unroll
      for (int j = 0; j < 4; ++j) bfr[j] = *(const bf16x8*)(Bb0 + j * 1024);
      if (t + 1 < NT) stageA(ns, 1, t + 1);
      __builtin_amdgcn_s_barrier();
      asm volatile("s_waitcnt lgkmcnt(0)" ::: "memory");
      __builtin_amdgcn_sched_barrier(0);
      __builtin_amdgcn_s_setprio(1);
#pragma unroll
      for (int f = 0; f < 4; ++f)
#pragma unroll
        for (int j = 0; j < 4; ++j)
          acc[f][j] = __builtin_amdgcn_mfma_f32_16x16x32_bf16(af[f], bfr[j], acc[f][j], 0, 0, 0);
      __builtin_amdgcn_s_setprio(0);
      __builtin_amdgcn_s_barrier();
      // ---- P2: frags A[4-7][ks0]; stage B[ks0]@t+2
#pragma unroll
      for (int f = 0; f < 4; ++f) af[f] = *(const bf16x8*)(Ab0 + (4 + f) * 1024);
      if (t + 2 < NT) stageB(s, 0, t + 2);
      __builtin_amdgcn_s_barrier();
      asm volatile("s_waitcnt lgkmcnt(0)" ::: "memory");
      __builtin_amdgcn_sched_barrier(0);
      __builtin_amdgcn_s_setprio(1);
#pragma unroll
      for (int f = 0; f < 4; ++f)
#pragma unroll
        for (int j = 0; j < 4; ++j)
          acc[4 + f][j] =
              __builtin_amdgcn_mfma_f32_16x16x32_bf16(af[f], bfr[j], acc[4 + f][j], 0, 0, 0);
      __builtin_amdgcn_s_setprio(0);
      __builtin_amdgcn_s_barrier();
      // ---- P3: frags A[0-3][ks1], B[ks1]; stage A[ks0]@t+2
#pragma unroll
      for (int f = 0; f < 4; ++f) af[f] = *(const bf16x8*)(Ab1 + f * 1024);
#pragma unroll
      for (int j = 0; j < 4; ++j) bfr[j] = *(const bf16x8*)(Bb1 + j * 1024);
      if (t + 2 < NT) stageA(s, 0, t + 2);
      __builtin_amdgcn_s_barrier();
      asm volatile("s_waitcnt lgkmcnt(0)" ::: "memory");
      __builtin_amdgcn_sched_barrier(0);
      __builtin_amdgcn_s_setprio(1);
#pragma unroll
      for (int f = 0; f < 4; ++f)
#pragma unroll
        for (int j = 0; j < 4; ++j)
          acc[f][j] = __builtin_amdgcn_mfma_f32_16x16x32_bf16(af[f], bfr[j], acc[f][j], 0, 0, 0);
      __builtin_amdgcn_s_setprio(0);
      __builtin_amdgcn_s_barrier();
      // ---- P4: frags A[4-7][ks1]; stage B[ks1]@t+2; tile-end counted gate
#pragma unroll
      for (int f = 0; f < 4; ++f) af[f] = *(const bf16x8*)(Ab1 + (4 + f) * 1024);
      if (t + 2 < NT) stageB(s, 1, t + 2);
      __builtin_amdgcn_s_barrier();
      asm volatile("s_waitcnt lgkmcnt(0)" ::: "memory");
      __builtin_amdgcn_sched_barrier(0);
      __builtin_amdgcn_s_setprio(1);
#pragma unroll
      for (int f = 0; f < 4; ++f)
#pragma unroll
        for (int j = 0; j < 4; ++j)
          acc[4 + f][j] =
              __builtin_amdgcn_mfma_f32_16x16x32_bf16(af[f], bfr[j], acc[4 + f][j], 0, 0, 0);
      __builtin_amdgcn_s_setprio(0);
      if (t + 2 < NT) {
        asm volatile("s_waitcnt vmcnt(6)" ::: "memory");  // tile t+1 landed; 3 regions in flight
      } else {
        asm volatile("s_waitcnt vmcnt(0)" ::: "memory");
      }
      __builtin_amdgcn_s_barrier();
    } else {
      // ---- P1 (ks0): frags A[0-3][ks0], B[ks0]; stage ks1@t+1
#pragma unroll
      for (int f = 0; f < 4; ++f) af[f] = *(const bf16x8*)(Ab0 + f * 1024);
#pragma unroll
      for (int j = 0; j < 4; ++j) bfr[j] = *(const bf16x8*)(Bb0 + j * 1024);
      if (t + 1 < NT) { stageA(ns, 1, t + 1); stageB(ns, 1, t + 1); }
      __builtin_amdgcn_s_barrier();
      asm volatile("s_waitcnt lgkmcnt(0)" ::: "memory");
      __builtin_amdgcn_sched_barrier(0);
      __builtin_amdgcn_s_setprio(1);
#pragma unroll
      for (int f = 0; f < 4; ++f)
#pragma unroll
        for (int j = 0; j < 4; ++j)
          acc[f][j] = __builtin_amdgcn_mfma_f32_16x16x32_bf16(af[f], bfr[j], acc[f][j], 0, 0, 0);
      __builtin_amdgcn_s_setprio(0);
      __builtin_amdgcn_s_barrier();
      // ---- P2 (ks1): frags A[ks1], B[ks1]; stage ks0@t+2; tile-end counted gate
#pragma unroll
      for (int f = 0; f < 4; ++f) af[f] = *(const bf16x8*)(Ab1 + f * 1024);
#pragma unroll
      for (int j = 0; j < 4; ++j) bfr[j] = *(const bf16x8*)(Bb1 + j * 1024);
      if (t + 2 < NT) { stageA(s, 0, t + 2); stageB(s, 0, t + 2); }
      __builtin_amdgcn_s_barrier();
      asm volatile("s_waitcnt lgkmcnt(0)" ::: "memory");
      __builtin_amdgcn_sched_barrier(0);
      __builtin_amdgcn_s_setprio(1);
#pragma unroll
      for (int f = 0; f < 4; ++f)
#pragma unroll
        for (int j = 0; j < 4; ++j)
          acc[f][j] = __builtin_amdgcn_mfma_f32_16x16x32_bf16(af[f], bfr[j], acc[f][j], 0, 0, 0);
      __builtin_amdgcn_s_setprio(0);
      if (t + 2 < NT) {
        asm volatile("s_waitcnt vmcnt(3)" ::: "memory");  // tile t+1 landed; 1 region in flight
      } else {
        asm volatile("s_waitcnt vmcnt(0)" ::: "memory");
      }
      __builtin_amdgcn_s_barrier();
    }
  }

  // epilogue: rows m0 = bm*256+wmi*MW+fr*16+g*4 (+r), col n = bn*BN+wni*64+nf*16+c
#pragma unroll
  for (int nf = 0; nf < 4; ++nf) {
    const int n = bn * BN + wni * 64 + nf * 16 + c;
    float bi = 0.f;
    if (MODE != 0) bi = bias[n];
#pragma unroll
    for (int fr = 0; fr < NAF; ++fr) {
      const int m0 = bm * 256 + wmi * MW + fr * 16 + g * 4;
      if (MODE == 0) {
        const int w = n >> 10, n1 = n & 1023, h = n1 >> 6, sidx = n1 & 63;
        const int b2 = m0 >> 11, t0 = m0 & 2047;
        if (w == 0) {
#pragma unroll
          for (int r = 0; r < 4; ++r)
            qo[(size_t)(b2 * Hc + h) * (Tc * HSc) + (size_t)(t0 + r) * HSc + sidx] =
                (bf16)(acc[fr][nf][r] * 0.125f);
        } else if (w == 1) {
#pragma unroll
          for (int r = 0; r < 4; ++r)
            ko[(size_t)(b2 * Hc + h) * (Tc * HSc) + (size_t)(t0 + r) * HSc + sidx] =
                (bf16)acc[fr][nf][r];
        } else {
          bf16x4 pk;
#pragma unroll
          for (int r = 0; r < 4; ++r) pk[r] = (bf16)acc[fr][nf][r];
          *(bf16x4*)&vto[((size_t)(b2 * Hc + h) * HSc + sidx) * Tc + t0] = pk;
        }
      } else if (MODE == 1 || MODE == 3) {
#pragma unroll
        for (int r = 0; r < 4; ++r) {
          const size_t idx = (size_t)(m0 + r) * NSTR + n;
          outf[idx] = acc[fr][nf][r] + bi + resid[idx];
        }
      } else {
#pragma unroll
        for (int r = 0; r < 4; ++r)
          outb[(size_t)(m0 + r) * NSTR + n] = (bf16)fmaxf(acc[fr][nf][r] + bi, 0.f);
      }
    }
  }
}

// ---------------- causal flash attention (unchanged from R3)
__global__ __launch_bounds__(256, 2) void attn_kernel(const bf16* __restrict__ q,
                                                      const bf16* __restrict__ k,
                                                      const bf16* __restrict__ vt,
                                                      bf16* __restrict__ ctx) {
  __shared__ __attribute__((aligned(16))) bf16 Kl[2][4096];
  __shared__ __attribute__((aligned(16))) bf16 Vl[2][4096];
  __shared__ __attribute__((aligned(16))) bf16 P[4][32][72];
  const int d0 = blockIdx.x;
  const int L = (d0 & 7) * 64 + (d0 >> 3);
  const int bh = L >> 3, p = L & 7;
  const int tid = threadIdx.x;
  const int wid = tid >> 6, lane = tid & 63;
  const int g = lane >> 4, c = lane & 15;
  const bf16* qh = q + (size_t)bh * Tc * HSc;
  const char* kh = (const char*)(k + (size_t)bh * Tc * HSc);
  const char* vh = (const char*)(vt + (size_t)bh * HSc * Tc);
  const int b = bh >> 4, h = bh & 15;

  const int sw = ((lane >> 3) & 7) << 4;
  const int soK = (lane * 16) ^ sw;
  const int vrow = lane >> 3;
  const int vcol = ((lane & 7) * 16) ^ sw;
  const int rsw = (c & 7) << 4;

  for (int g2 = 0; g2 < 2; ++g2) {
    const int grp = g2 ? p : 15 - p;
    const int ktB = 2 * grp + 1;
    const int ktW = 2 * grp + (wid >> 1);
    const int row0 = grp * 128 + wid * 32;
    const bf16* qb = qh + (size_t)row0 * HSc;

    bf16x8 qf[2][2];
#pragma unroll
    for (int mi = 0; mi < 2; ++mi)
#pragma unroll
      for (int kk = 0; kk < 2; ++kk)
        qf[mi][kk] = *(const bf16x8*)&qb[(size_t)(mi * 16 + c) * HSc + kk * 32 + g * 8];

    f32x4 o[2][4];
    float m_[2][4], ls[2][4];
#pragma unroll
    for (int mi = 0; mi < 2; ++mi)
#pragma unroll
      for (int r = 0; r < 4; ++r) {
        m_[mi][r] = -1e30f;
        ls[mi][r] = 0.f;
#pragma unroll
        for (int di = 0; di < 4; ++di) o[mi][di][r] = 0.f;
      }

    auto stage = [&](int buf, int kt) {
      const char* kb = kh + (size_t)kt * 8192;
      const char* vb = vh + (size_t)kt * 128;
#pragma unroll
      for (int i = 0; i < 4; ++i) {
        const int idx = wid * 4 + i;
        if (idx < 8) {
          load_lds16(kb + idx * 1024 + soK, (char*)&Kl[buf][0] + idx * 1024);
        } else {
          const int j = idx - 8;
          load_lds16(vb + (size_t)(j * 8 + vrow) * (Tc * 2) + vcol,
                     (char*)&Vl[buf][0] + j * 1024);
        }
      }
    };

    stage(0, 0);
    __syncthreads();
    int cur = 0;
    for (int kt = 0; kt <= ktB; ++kt) {
      if (kt < ktB) stage(cur ^ 1, kt + 1);
      if (kt <= ktW) {
        const char* Kb = (const char*)&Kl[cur][0];
        bf16x8 kf[4][2];
#pragma unroll
        for (int ni = 0; ni < 4; ++ni)
#pragma unroll
          for (int kk = 0; kk < 2; ++kk)
            kf[ni][kk] = *(const bf16x8*)(Kb + (ni * 16 + c) * 128 +
                                          (((kk << 6) | (g << 4)) ^ rsw));
        f32x4 s[2][4];
#pragma unroll
        for (int mi = 0; mi < 2; ++mi)
#pragma unroll
          for (int ni = 0; ni < 4; ++ni)
#pragma unroll
            for (int r = 0; r < 4; ++r) s[mi][ni][r] = 0.f;
        __builtin_amdgcn_s_setprio(1);
#pragma unroll
        for (int kk = 0; kk < 2; ++kk)
#pragma unroll
          for (int mi = 0; mi < 2; ++mi)
#pragma unroll
            for (int ni = 0; ni < 4; ++ni)
              s[mi][ni] = __builtin_amdgcn_mfma_f32_16x16x32_bf16(qf[mi][kk], kf[ni][kk],
                                                                  s[mi][ni], 0, 0, 0);
        __builtin_amdgcn_s_setprio(0);

        if (kt == ktW) {
#pragma unroll
          for (int mi = 0; mi < 2; ++mi)
#pragma unroll
            for (int ni = 0; ni < 4; ++ni)
#pragma unroll
              for (int r = 0; r < 4; ++r) {
                const int row = row0 + mi * 16 + g * 4 + r;
                const int col = kt * 64 + ni * 16 + c;
                if (col > row) s[mi][ni][r] = -1e30f;
              }
        }

        float pm[2][4];
        int need = 0;
#pragma unroll
        for (int mi = 0; mi < 2; ++mi)
#pragma unroll
          for (int r = 0; r < 4; ++r) {
            pm[mi][r] =
                fmaxf(fmaxf(s[mi][0][r], s[mi][1][r]), fmaxf(s[mi][2][r], s[mi][3][r]));
            need |= (pm[mi][r] > m_[mi][r] + 8.f) ? 1 : 0;
          }
        if (__any(need)) {
#pragma unroll
          for (int mi = 0; mi < 2; ++mi)
#pragma unroll
            for (int r = 0; r < 4; ++r) {
              float mx = pm[mi][r];
#pragma unroll
              for (int msk = 1; msk < 16; msk <<= 1) mx = fmaxf(mx, __shfl_xor(mx, msk));
              const float mn = fmaxf(m_[mi][r], mx);
              const float al = __expf(m_[mi][r] - mn);
              m_[mi][r] = mn;
              ls[mi][r] *= al;
#pragma unroll
              for (int di = 0; di < 4; ++di) o[mi][di][r] *= al;
            }
        }
#pragma unroll
        for (int mi = 0; mi < 2; ++mi)
#pragma unroll
          for (int r = 0; r < 4; ++r) {
            float ps = 0.f;
#pragma unroll
            for (int ni = 0; ni < 4; ++ni) {
              const float pv = __expf(s[mi][ni][r] - m_[mi][r]);
              ps += pv;
              P[wid][mi * 16 + g * 4 + r][ni * 16 + c] = (bf16)pv;
            }
            ls[mi][r] += ps;
          }
        asm volatile("s_waitcnt lgkmcnt(0)" ::: "memory");
        __builtin_amdgcn_sched_barrier(0);

        bf16x8 pf[2][2];
#pragma unroll
        for (int mi = 0; mi < 2; ++mi)
#pragma unroll
          for (int kk = 0; kk < 2; ++kk)
            pf[mi][kk] = *(const bf16x8*)&P[wid][mi * 16 + c][kk * 32 + g * 8];
        const char* Vb = (const char*)&Vl[cur][0];
#pragma unroll
        for (int di = 0; di < 4; ++di) {
          bf16x8 vf0 = *(const bf16x8*)(Vb + (di * 16 + c) * 128 + ((g << 4) ^ rsw));
          bf16x8 vf1 =
              *(const bf16x8*)(Vb + (di * 16 + c) * 128 + (((1 << 6) | (g << 4)) ^ rsw));
          __builtin_amdgcn_s_setprio(1);
#pragma unroll
          for (int mi = 0; mi < 2; ++mi) {
            o[mi][di] = __builtin_amdgcn_mfma_f32_16x16x32_bf16(pf[mi][0], vf0, o[mi][di], 0, 0, 0);
            o[mi][di] = __builtin_amdgcn_mfma_f32_16x16x32_bf16(pf[mi][1], vf1, o[mi][di], 0, 0, 0);
          }
          __builtin_amdgcn_s_setprio(0);
        }
      }
      __syncthreads();
      cur ^= 1;
    }

#pragma unroll
    for (int mi = 0; mi < 2; ++mi)
#pragma unroll
      for (int r = 0; r < 4; ++r) {
        float l = ls[mi][r];
#pragma unroll
        for (int msk = 1; msk < 16; msk <<= 1) l += __shfl_xor(l, msk);
        const float inv = 1.f / l;
        const int t = row0 + mi * 16 + g * 4 + r;
#pragma unroll
        for (int di = 0; di < 4; ++di)
          ctx[((size_t)(b * Tc + t)) * Dc + h * 64 + di * 16 + c] =
              (bf16)(o[mi][di][r] * inv);
      }
  }
}

// ---------------- launch ----------------
extern "C" void kernel_launch(void* const* d_in, const int* in_sizes, int n_in,
                              void* d_out, int out_size, void* d_ws, size_t ws_size,
                              hipStream_t stream) {
  (void)in_sizes; (void)n_in; (void)out_size; (void)ws_size;
  const float* x      = (const float*)d_in[0];
  const float* ln1_g  = (const float*)d_in[1];
  const float* ln1_b  = (const float*)d_in[2];
  const float* wq     = (const float*)d_in[3];
  const float* wk     = (const float*)d_in[4];
  const float* wv     = (const float*)d_in[5];
  const float* w_proj = (const float*)d_in[6];
  const float* b_proj = (const float*)d_in[7];
  const float* ln2_g  = (const float*)d_in[8];
  const float* ln2_b  = (const float*)d_in[9];
  const float* w1     = (const float*)d_in[10];
  const float* b1     = (const float*)d_in[11];
  const float* w2     = (const float*)d_in[12];
  const float* b2     = (const float*)d_in[13];
  float* out = (float*)d_out;
  char* ws = (char*)d_ws;

  bf16* qbuf   = (bf16*)(ws + 0);
  bf16* kbuf   = (bf16*)(ws + 16777216);
  bf16* vtbuf  = (bf16*)(ws + 33554432);
  bf16* ctxbuf = (bf16*)(ws + 50331648);
  bf16* wqkvT  = (bf16*)(ws + 67108864);
  bf16* hbuf   = (bf16*)(ws + 0);  // aliases q/k/vt/ctx, dead by FFN1
  bf16* wprojT = (bf16*)(ws + 73400320);
  bf16* w1T    = (bf16*)(ws + 75497472);
  bf16* w2T    = (bf16*)(ws + 83886080);
  bf16* xn     = (bf16*)(ws + 92274688);
  float* x1buf = (float*)(ws + 109051904);

  repack_qkv_kernel<<<dim3(16, 48), dim3(64, 4), 0, stream>>>(wq, wk, wv, wqkvT);
  transpose_to_bf16_kernel<<<dim3(16, 16), dim3(64, 4), 0, stream>>>(w_proj, wprojT, 1024, 1024);
  transpose_to_bf16_kernel<<<dim3(16, 64), dim3(64, 4), 0, stream>>>(w1, w1T, 1024, 4096);
  transpose_to_bf16_kernel<<<dim3(64, 16), dim3(64, 4), 0, stream>>>(w2, w2T, 4096, 1024);

  ln_kernel<<<Mrows, 256, 0, stream>>>(x, ln1_g, ln1_b, xn);
  gemm9p_kernel<0, 1024, 128><<<dim3(32, 24), 512, 0, stream>>>(
      xn, wqkvT, nullptr, nullptr, nullptr, nullptr, qbuf, kbuf, vtbuf);
  attn_kernel<<<512, 256, 0, stream>>>(qbuf, kbuf, vtbuf, ctxbuf);
  gemm9p_kernel<1, 1024, 128><<<dim3(32, 8), 512, 0, stream>>>(
      ctxbuf, wprojT, b_proj, x, x1buf, nullptr, nullptr, nullptr, nullptr);
  ln_kernel<<<Mrows, 256, 0, stream>>>(x1buf, ln2_g, ln2_b, xn);
  gemm9p_kernel<2, 1024, 256><<<dim3(32, 16), 512, 0, stream>>>(
      xn, w1T, b1, nullptr, nullptr, hbuf, nullptr, nullptr, nullptr);
  gemm9p_kernel<3, 4096, 128><<<dim3(32, 8), 512, 0, stream>>>(
      hbuf, w2T, b2, x1buf, out, nullptr, nullptr, nullptr, nullptr);
}

// Round 10
// 368.741 us; speedup vs baseline: 1.1873x; 1.0194x over previous
//
#include <hip/hip_runtime.h>

typedef __bf16 bf16;
typedef __attribute__((ext_vector_type(8))) __bf16 bf16x8;
typedef __attribute__((ext_vector_type(4))) __bf16 bf16x4;
typedef __attribute__((ext_vector_type(4))) float f32x4;

static constexpr int Bc = 4, Tc = 2048, Dc = 1024, Hc = 16, HSc = 64, DFF = 4096;
static constexpr int Mrows = Bc * Tc;  // 8192

#define DEV __device__ __forceinline__

DEV void load_lds16(const void* g, void* l) {
  __builtin_amdgcn_global_load_lds(
      (const __attribute__((address_space(1))) void*)g,
      (__attribute__((address_space(3))) void*)l, 16, 0, 0);
}

// ---------------- weight repack: wq/wk/wv [H,D,HS] -> WqkvT [3072(n)][1024(k=d)] bf16
__global__ void repack_qkv_kernel(const float* __restrict__ wq,
                                  const float* __restrict__ wk,
                                  const float* __restrict__ wv,
                                  bf16* __restrict__ dst) {
  __shared__ float tile[64][65];
  const int dblk = blockIdx.x;
  const int z = blockIdx.y;
  const int w = z >> 4, h = z & 15;
  const float* src = (w == 0 ? wq : (w == 1 ? wk : wv)) + (size_t)h * Dc * HSc;
  const int tx = threadIdx.x, ty = threadIdx.y;
#pragma unroll
  for (int i = 0; i < 16; ++i)
    tile[ty + i * 4][tx] = src[(size_t)(dblk * 64 + ty + i * 4) * HSc + tx];
  __syncthreads();
#pragma unroll
  for (int i = 0; i < 16; ++i) {
    const int s = ty + i * 4;
    dst[((size_t)w * 1024 + h * 64 + s) * Dc + dblk * 64 + tx] = (bf16)tile[tx][s];
  }
}

// ---------------- generic [R][C] f32 -> [C][R] bf16 transpose
__global__ void transpose_to_bf16_kernel(const float* __restrict__ src,
                                         bf16* __restrict__ dst, int R, int C) {
  __shared__ float tile[64][65];
  const int r0 = blockIdx.x * 64, c0 = blockIdx.y * 64;
  const int tx = threadIdx.x, ty = threadIdx.y;
#pragma unroll
  for (int i = 0; i < 16; ++i)
    tile[ty + i * 4][tx] = src[(size_t)(r0 + ty + i * 4) * C + c0 + tx];
  __syncthreads();
#pragma unroll
  for (int i = 0; i < 16; ++i)
    dst[(size_t)(c0 + ty + i * 4) * R + r0 + tx] = (bf16)tile[tx][ty + i * 4];
}

// ---------------- LayerNorm row kernel: f32 in -> bf16 out
__global__ __launch_bounds__(256) void ln_kernel(const float* __restrict__ x,
                                                 const float* __restrict__ gam,
                                                 const float* __restrict__ bet,
                                                 bf16* __restrict__ out) {
  const int row = blockIdx.x;
  const int t = threadIdx.x;
  const float4 v = ((const float4*)(x + (size_t)row * Dc))[t];
  float s = v.x + v.y + v.z + v.w;
  float s2 = v.x * v.x + v.y * v.y + v.z * v.z + v.w * v.w;
#pragma unroll
  for (int m = 1; m < 64; m <<= 1) {
    s += __shfl_xor(s, m);
    s2 += __shfl_xor(s2, m);
  }
  __shared__ float red[8];
  const int wid = t >> 6;
  if ((t & 63) == 0) { red[wid * 2] = s; red[wid * 2 + 1] = s2; }
  __syncthreads();
  s = red[0] + red[2] + red[4] + red[6];
  s2 = red[1] + red[3] + red[5] + red[7];
  const float mean = s * (1.f / Dc);
  const float var = s2 * (1.f / Dc) - mean * mean;
  const float rstd = rsqrtf(var + 1e-5f);
  const float4 gv = ((const float4*)gam)[t];
  const float4 bv = ((const float4*)bet)[t];
  bf16x4 o;
  o[0] = (bf16)((v.x - mean) * rstd * gv.x + bv.x);
  o[1] = (bf16)((v.y - mean) * rstd * gv.y + bv.y);
  o[2] = (bf16)((v.z - mean) * rstd * gv.z + bv.z);
  o[3] = (bf16)((v.w - mean) * rstd * gv.w + bv.w);
  *(bf16x4*)(out + (size_t)row * Dc + t * 4) = o;
}

// ---------------- GEMM v7 (high-occupancy TLP): BM=BN=128, BK=32, 4 waves
// (2Mx2N, per-wave 64x64), 32KB LDS -> 3-4 blocks/CU. 2-side in-place rotation,
// depth-2 prefetch, counted vmcnt(4) gate, R9's verified 2-way swizzle.
// Per K-tile: {8 frag reads; lgkm0; barrier; stage(t+2->[s]); 16 MFMA;
// vmcnt(4); barrier}. Independent blocks provide the stall-hiding.
template <int MODE, int KTOT>
__global__ __launch_bounds__(256) void gemmho_kernel(
    const bf16* __restrict__ A, const bf16* __restrict__ BT,
    const float* __restrict__ bias, const float* __restrict__ resid,
    float* __restrict__ outf, bf16* __restrict__ outb,
    bf16* __restrict__ qo, bf16* __restrict__ ko, bf16* __restrict__ vto) {
  constexpr int NT = KTOT / 32;
  constexpr int NSTR = (MODE == 2) ? 4096 : 1024;

  __shared__ __attribute__((aligned(16))) bf16 As[2][128 * 32];
  __shared__ __attribute__((aligned(16))) bf16 Bs[2][128 * 32];

  const int tid = threadIdx.x;
  const int wid = tid >> 6, lane = tid & 63;
  const int g = (lane >> 4) & 3, c = lane & 15;
  const int wm = wid >> 1, wn = wid & 1;
  const int bm = blockIdx.x, bn = blockIdx.y;

  f32x4 acc[4][4];
#pragma unroll
  for (int i = 0; i < 4; ++i)
#pragma unroll
    for (int j = 0; j < 4; ++j)
#pragma unroll
      for (int r = 0; r < 4; ++r) acc[i][j][r] = 0.f;

  const char* Agl = (const char*)A;
  const char* Bgl = (const char*)BT;
  const int grow = tid >> 2;  // 0..63: row within a 4KB call (64 rows x 64B)
  // dest unit = tid&3 (linear); source unit = dest ^ ((row>>1)&3)
  const int gsw = (((tid & 3) ^ ((tid >> 3) & 3)) << 4);

  auto stage = [&](int side, int kt) {
#pragma unroll
    for (int a = 0; a < 2; ++a)
      load_lds16(Agl + ((size_t)(bm * 128 + a * 64 + grow) * KTOT + kt * 32) * 2 + gsw,
                 (char*)&As[side][0] + a * 4096 + tid * 16);
#pragma unroll
    for (int b = 0; b < 2; ++b)
      load_lds16(Bgl + ((size_t)(bn * 128 + b * 64 + grow) * KTOT + kt * 32) * 2 + gsw,
                 (char*)&Bs[side][0] + b * 4096 + tid * 16);
  };

  // frag-read offsets: row = wave_base + f*16 + c -> (row>>1)&3 == (c>>1)&3
  const int rsw = ((c >> 1) & 3) << 4;
  const int aoff = (wm * 64 + c) * 64 + ((g * 16) ^ rsw);
  const int boff = (wn * 64 + c) * 64 + ((g * 16) ^ rsw);

  stage(0, 0);
  stage(1, 1);
  asm volatile("s_waitcnt vmcnt(4)" ::: "memory");  // tile 0 landed; tile 1 in flight
  __builtin_amdgcn_s_barrier();

  for (int t = 0; t < NT; ++t) {
    const int s = t & 1;
    const char* Ab = (const char*)&As[s][0] + aoff;
    const char* Bb = (const char*)&Bs[s][0] + boff;
    bf16x8 af[4], bfr[4];
#pragma unroll
    for (int f = 0; f < 4; ++f) af[f] = *(const bf16x8*)(Ab + f * 1024);
#pragma unroll
    for (int j = 0; j < 4; ++j) bfr[j] = *(const bf16x8*)(Bb + j * 1024);
    asm volatile("s_waitcnt lgkmcnt(0)" ::: "memory");
    __builtin_amdgcn_sched_barrier(0);
    __builtin_amdgcn_s_barrier();  // all waves drained reads of [s] -> writable
    if (t + 2 < NT) stage(s, t + 2);
    __builtin_amdgcn_s_setprio(1);
#pragma unroll
    for (int f = 0; f < 4; ++f)
#pragma unroll
      for (int j = 0; j < 4; ++j)
        acc[f][j] = __builtin_amdgcn_mfma_f32_16x16x32_bf16(af[f], bfr[j], acc[f][j], 0, 0, 0);
    __builtin_amdgcn_s_setprio(0);
    if (t + 2 < NT) {
      asm volatile("s_waitcnt vmcnt(4)" ::: "memory");  // tile t+1 landed; t+2 in flight
    } else {
      asm volatile("s_waitcnt vmcnt(0)" ::: "memory");
    }
    __builtin_amdgcn_s_barrier();  // next side published to all waves
  }

  // epilogue: rows m0 = bm*128+wm*64+fr*16+g*4 (+r), col n = bn*128+wn*64+nf*16+c
#pragma unroll
  for (int nf = 0; nf < 4; ++nf) {
    const int n = bn * 128 + wn * 64 + nf * 16 + c;
    float bi = 0.f;
    if (MODE != 0) bi = bias[n];
#pragma unroll
    for (int fr = 0; fr < 4; ++fr) {
      const int m0 = bm * 128 + wm * 64 + fr * 16 + g * 4;
      if (MODE == 0) {
        const int w = n >> 10, n1 = n & 1023, h = n1 >> 6, sidx = n1 & 63;
        const int b2 = m0 >> 11, t0 = m0 & 2047;
        if (w == 0) {
#pragma unroll
          for (int r = 0; r < 4; ++r)
            qo[(size_t)(b2 * Hc + h) * (Tc * HSc) + (size_t)(t0 + r) * HSc + sidx] =
                (bf16)(acc[fr][nf][r] * 0.125f);
        } else if (w == 1) {
#pragma unroll
          for (int r = 0; r < 4; ++r)
            ko[(size_t)(b2 * Hc + h) * (Tc * HSc) + (size_t)(t0 + r) * HSc + sidx] =
                (bf16)acc[fr][nf][r];
        } else {
          bf16x4 pk;
#pragma unroll
          for (int r = 0; r < 4; ++r) pk[r] = (bf16)acc[fr][nf][r];
          *(bf16x4*)&vto[((size_t)(b2 * Hc + h) * HSc + sidx) * Tc + t0] = pk;
        }
      } else if (MODE == 1 || MODE == 3) {
#pragma unroll
        for (int r = 0; r < 4; ++r) {
          const size_t idx = (size_t)(m0 + r) * NSTR + n;
          outf[idx] = acc[fr][nf][r] + bi + resid[idx];
        }
      } else {
#pragma unroll
        for (int r = 0; r < 4; ++r)
          outb[(size_t)(m0 + r) * NSTR + n] = (bf16)fmaxf(acc[fr][nf][r] + bi, 0.f);
      }
    }
  }
}

// ---------------- causal flash attention (unchanged from R3)
__global__ __launch_bounds__(256, 2) void attn_kernel(const bf16* __restrict__ q,
                                                      const bf16* __restrict__ k,
                                                      const bf16* __restrict__ vt,
                                                      bf16* __restrict__ ctx) {
  __shared__ __attribute__((aligned(16))) bf16 Kl[2][4096];
  __shared__ __attribute__((aligned(16))) bf16 Vl[2][4096];
  __shared__ __attribute__((aligned(16))) bf16 P[4][32][72];
  const int d0 = blockIdx.x;
  const int L = (d0 & 7) * 64 + (d0 >> 3);
  const int bh = L >> 3, p = L & 7;
  const int tid = threadIdx.x;
  const int wid = tid >> 6, lane = tid & 63;
  const int g = lane >> 4, c = lane & 15;
  const bf16* qh = q + (size_t)bh * Tc * HSc;
  const char* kh = (const char*)(k + (size_t)bh * Tc * HSc);
  const char* vh = (const char*)(vt + (size_t)bh * HSc * Tc);
  const int b = bh >> 4, h = bh & 15;

  const int sw = ((lane >> 3) & 7) << 4;
  const int soK = (lane * 16) ^ sw;
  const int vrow = lane >> 3;
  const int vcol = ((lane & 7) * 16) ^ sw;
  const int rsw = (c & 7) << 4;

  for (int g2 = 0; g2 < 2; ++g2) {
    const int grp = g2 ? p : 15 - p;
    const int ktB = 2 * grp + 1;
    const int ktW = 2 * grp + (wid >> 1);
    const int row0 = grp * 128 + wid * 32;
    const bf16* qb = qh + (size_t)row0 * HSc;

    bf16x8 qf[2][2];
#pragma unroll
    for (int mi = 0; mi < 2; ++mi)
#pragma unroll
      for (int kk = 0; kk < 2; ++kk)
        qf[mi][kk] = *(const bf16x8*)&qb[(size_t)(mi * 16 + c) * HSc + kk * 32 + g * 8];

    f32x4 o[2][4];
    float m_[2][4], ls[2][4];
#pragma unroll
    for (int mi = 0; mi < 2; ++mi)
#pragma unroll
      for (int r = 0; r < 4; ++r) {
        m_[mi][r] = -1e30f;
        ls[mi][r] = 0.f;
#pragma unroll
        for (int di = 0; di < 4; ++di) o[mi][di][r] = 0.f;
      }

    auto stage = [&](int buf, int kt) {
      const char* kb = kh + (size_t)kt * 8192;
      const char* vb = vh + (size_t)kt * 128;
#pragma unroll
      for (int i = 0; i < 4; ++i) {
        const int idx = wid * 4 + i;
        if (idx < 8) {
          load_lds16(kb + idx * 1024 + soK, (char*)&Kl[buf][0] + idx * 1024);
        } else {
          const int j = idx - 8;
          load_lds16(vb + (size_t)(j * 8 + vrow) * (Tc * 2) + vcol,
                     (char*)&Vl[buf][0] + j * 1024);
        }
      }
    };

    stage(0, 0);
    __syncthreads();
    int cur = 0;
    for (int kt = 0; kt <= ktB; ++kt) {
      if (kt < ktB) stage(cur ^ 1, kt + 1);
      if (kt <= ktW) {
        const char* Kb = (const char*)&Kl[cur][0];
        bf16x8 kf[4][2];
#pragma unroll
        for (int ni = 0; ni < 4; ++ni)
#pragma unroll
          for (int kk = 0; kk < 2; ++kk)
            kf[ni][kk] = *(const bf16x8*)(Kb + (ni * 16 + c) * 128 +
                                          (((kk << 6) | (g << 4)) ^ rsw));
        f32x4 s[2][4];
#pragma unroll
        for (int mi = 0; mi < 2; ++mi)
#pragma unroll
          for (int ni = 0; ni < 4; ++ni)
#pragma unroll
            for (int r = 0; r < 4; ++r) s[mi][ni][r] = 0.f;
        __builtin_amdgcn_s_setprio(1);
#pragma unroll
        for (int kk = 0; kk < 2; ++kk)
#pragma unroll
          for (int mi = 0; mi < 2; ++mi)
#pragma unroll
            for (int ni = 0; ni < 4; ++ni)
              s[mi][ni] = __builtin_amdgcn_mfma_f32_16x16x32_bf16(qf[mi][kk], kf[ni][kk],
                                                                  s[mi][ni], 0, 0, 0);
        __builtin_amdgcn_s_setprio(0);

        if (kt == ktW) {
#pragma unroll
          for (int mi = 0; mi < 2; ++mi)
#pragma unroll
            for (int ni = 0; ni < 4; ++ni)
#pragma unroll
              for (int r = 0; r < 4; ++r) {
                const int row = row0 + mi * 16 + g * 4 + r;
                const int col = kt * 64 + ni * 16 + c;
                if (col > row) s[mi][ni][r] = -1e30f;
              }
        }

        float pm[2][4];
        int need = 0;
#pragma unroll
        for (int mi = 0; mi < 2; ++mi)
#pragma unroll
          for (int r = 0; r < 4; ++r) {
            pm[mi][r] =
                fmaxf(fmaxf(s[mi][0][r], s[mi][1][r]), fmaxf(s[mi][2][r], s[mi][3][r]));
            need |= (pm[mi][r] > m_[mi][r] + 8.f) ? 1 : 0;
          }
        if (__any(need)) {
#pragma unroll
          for (int mi = 0; mi < 2; ++mi)
#pragma unroll
            for (int r = 0; r < 4; ++r) {
              float mx = pm[mi][r];
#pragma unroll
              for (int msk = 1; msk < 16; msk <<= 1) mx = fmaxf(mx, __shfl_xor(mx, msk));
              const float mn = fmaxf(m_[mi][r], mx);
              const float al = __expf(m_[mi][r] - mn);
              m_[mi][r] = mn;
              ls[mi][r] *= al;
#pragma unroll
              for (int di = 0; di < 4; ++di) o[mi][di][r] *= al;
            }
        }
#pragma unroll
        for (int mi = 0; mi < 2; ++mi)
#pragma unroll
          for (int r = 0; r < 4; ++r) {
            float ps = 0.f;
#pragma unroll
            for (int ni = 0; ni < 4; ++ni) {
              const float pv = __expf(s[mi][ni][r] - m_[mi][r]);
              ps += pv;
              P[wid][mi * 16 + g * 4 + r][ni * 16 + c] = (bf16)pv;
            }
            ls[mi][r] += ps;
          }
        asm volatile("s_waitcnt lgkmcnt(0)" ::: "memory");
        __builtin_amdgcn_sched_barrier(0);

        bf16x8 pf[2][2];
#pragma unroll
        for (int mi = 0; mi < 2; ++mi)
#pragma unroll
          for (int kk = 0; kk < 2; ++kk)
            pf[mi][kk] = *(const bf16x8*)&P[wid][mi * 16 + c][kk * 32 + g * 8];
        const char* Vb = (const char*)&Vl[cur][0];
#pragma unroll
        for (int di = 0; di < 4; ++di) {
          bf16x8 vf0 = *(const bf16x8*)(Vb + (di * 16 + c) * 128 + ((g << 4) ^ rsw));
          bf16x8 vf1 =
              *(const bf16x8*)(Vb + (di * 16 + c) * 128 + (((1 << 6) | (g << 4)) ^ rsw));
          __builtin_amdgcn_s_setprio(1);
#pragma unroll
          for (int mi = 0; mi < 2; ++mi) {
            o[mi][di] = __builtin_amdgcn_mfma_f32_16x16x32_bf16(pf[mi][0], vf0, o[mi][di], 0, 0, 0);
            o[mi][di] = __builtin_amdgcn_mfma_f32_16x16x32_bf16(pf[mi][1], vf1, o[mi][di], 0, 0, 0);
          }
          __builtin_amdgcn_s_setprio(0);
        }
      }
      __syncthreads();
      cur ^= 1;
    }

#pragma unroll
    for (int mi = 0; mi < 2; ++mi)
#pragma unroll
      for (int r = 0; r < 4; ++r) {
        float l = ls[mi][r];
#pragma unroll
        for (int msk = 1; msk < 16; msk <<= 1) l += __shfl_xor(l, msk);
        const float inv = 1.f / l;
        const int t = row0 + mi * 16 + g * 4 + r;
#pragma unroll
        for (int di = 0; di < 4; ++di)
          ctx[((size_t)(b * Tc + t)) * Dc + h * 64 + di * 16 + c] =
              (bf16)(o[mi][di][r] * inv);
      }
  }
}

// ---------------- launch ----------------
extern "C" void kernel_launch(void* const* d_in, const int* in_sizes, int n_in,
                              void* d_out, int out_size, void* d_ws, size_t ws_size,
                              hipStream_t stream) {
  (void)in_sizes; (void)n_in; (void)out_size; (void)ws_size;
  const float* x      = (const float*)d_in[0];
  const float* ln1_g  = (const float*)d_in[1];
  const float* ln1_b  = (const float*)d_in[2];
  const float* wq     = (const float*)d_in[3];
  const float* wk     = (const float*)d_in[4];
  const float* wv     = (const float*)d_in[5];
  const float* w_proj = (const float*)d_in[6];
  const float* b_proj = (const float*)d_in[7];
  const float* ln2_g  = (const float*)d_in[8];
  const float* ln2_b  = (const float*)d_in[9];
  const float* w1     = (const float*)d_in[10];
  const float* b1     = (const float*)d_in[11];
  const float* w2     = (const float*)d_in[12];
  const float* b2     = (const float*)d_in[13];
  float* out = (float*)d_out;
  char* ws = (char*)d_ws;

  bf16* qbuf   = (bf16*)(ws + 0);
  bf16* kbuf   = (bf16*)(ws + 16777216);
  bf16* vtbuf  = (bf16*)(ws + 33554432);
  bf16* ctxbuf = (bf16*)(ws + 50331648);
  bf16* wqkvT  = (bf16*)(ws + 67108864);
  bf16* hbuf   = (bf16*)(ws + 0);  // aliases q/k/vt/ctx, dead by FFN1
  bf16* wprojT = (bf16*)(ws + 73400320);
  bf16* w1T    = (bf16*)(ws + 75497472);
  bf16* w2T    = (bf16*)(ws + 83886080);
  bf16* xn     = (bf16*)(ws + 92274688);
  float* x1buf = (float*)(ws + 109051904);

  repack_qkv_kernel<<<dim3(16, 48), dim3(64, 4), 0, stream>>>(wq, wk, wv, wqkvT);
  transpose_to_bf16_kernel<<<dim3(16, 16), dim3(64, 4), 0, stream>>>(w_proj, wprojT, 1024, 1024);
  transpose_to_bf16_kernel<<<dim3(16, 64), dim3(64, 4), 0, stream>>>(w1, w1T, 1024, 4096);
  transpose_to_bf16_kernel<<<dim3(64, 16), dim3(64, 4), 0, stream>>>(w2, w2T, 4096, 1024);

  ln_kernel<<<Mrows, 256, 0, stream>>>(x, ln1_g, ln1_b, xn);
  gemmho_kernel<0, 1024><<<dim3(64, 24), 256, 0, stream>>>(
      xn, wqkvT, nullptr, nullptr, nullptr, nullptr, qbuf, kbuf, vtbuf);
  attn_kernel<<<512, 256, 0, stream>>>(qbuf, kbuf, vtbuf, ctxbuf);
  gemmho_kernel<1, 1024><<<dim3(64, 8), 256, 0, stream>>>(
      ctxbuf, wprojT, b_proj, x, x1buf, nullptr, nullptr, nullptr, nullptr);
  ln_kernel<<<Mrows, 256, 0, stream>>>(x1buf, ln2_g, ln2_b, xn);
  gemmho_kernel<2, 1024><<<dim3(64, 32), 256, 0, stream>>>(
      xn, w1T, b1, nullptr, nullptr, hbuf, nullptr, nullptr, nullptr);
  gemmho_kernel<3, 4096><<<dim3(64, 8), 256, 0, stream>>>(
      hbuf, w2T, b2, x1buf, out, nullptr, nullptr, nullptr, nullptr);
}